// Round 3
// baseline (1510.975 us; speedup 1.0000x reference)
//
// R1 baseline: pure-f32, correctness-first.
// pipeline: gemm(pre=x@W_enc+b) -> radix-select top64/row (+z scatter) ->
//           invperm -> sparse decode (both prefixes) + per-(b,t) SSE -> reduce.
// ws layout: pre 64MB | tk_idx 256KB | tk_val 256KB | ipos 256KB | part0/1 32KB
#include <hip/hip_runtime.h>
#include <hip/hip_bf16.h>
#include <stdint.h>

#define NB    1024
#define NT    4
#define NDIN  768
#define NSAE  16384
#define NK    64
#define KDIM  3072
#define PFX0  8192

__device__ __forceinline__ unsigned f2key(float f) {
    union { float f; unsigned u; } cv; cv.f = f;
    unsigned u = cv.u;
    return u ^ ((unsigned)((int)u >> 31) | 0x80000000u);  // monotonic float->uint
}

// ---------------- encoder GEMM: pre = x @ W_enc + b_enc ----------------
// A (1024,3072) row-major, B (3072,16384) row-major, 128x128 tile, BK=16,
// 256 thr, 8x8 microtile.
__global__ __launch_bounds__(256) void gemm_pre_kernel(
    const float* __restrict__ A, const float* __restrict__ Bm,
    const float* __restrict__ bias, float* __restrict__ pre)
{
    __shared__ float As[16][128];   // [k][m]
    __shared__ float Bs[16][128];   // [k][n]
    const int bn = blockIdx.x * 128;
    const int bm = blockIdx.y * 128;
    const int tid = threadIdx.x;
    const int tx = tid & 15;
    const int ty = tid >> 4;

    float acc[8][8];
#pragma unroll
    for (int i = 0; i < 8; ++i)
#pragma unroll
        for (int j = 0; j < 8; ++j) acc[i][j] = 0.f;

    for (int k0 = 0; k0 < KDIM; k0 += 16) {
        // A tile 128x16: 512 float4, 2/thread, transpose into As[k][m]
#pragma unroll
        for (int i = 0; i < 2; ++i) {
            const int idx = i * 256 + tid;
            const int r = idx >> 2;
            const int c = (idx & 3) << 2;
            const float4 v = *(const float4*)(A + (size_t)(bm + r) * KDIM + (k0 + c));
            As[c + 0][r] = v.x; As[c + 1][r] = v.y;
            As[c + 2][r] = v.z; As[c + 3][r] = v.w;
        }
        // B tile 16x128: contiguous float4
#pragma unroll
        for (int i = 0; i < 2; ++i) {
            const int idx = i * 256 + tid;
            const int r = idx >> 5;
            const int c = (idx & 31) << 2;
            *(float4*)(&Bs[r][c]) = *(const float4*)(Bm + (size_t)(k0 + r) * NSAE + (bn + c));
        }
        __syncthreads();
#pragma unroll
        for (int kk = 0; kk < 16; ++kk) {
            const float4 a0 = *(const float4*)(&As[kk][ty * 8]);
            const float4 a1 = *(const float4*)(&As[kk][ty * 8 + 4]);
            const float4 b0 = *(const float4*)(&Bs[kk][tx * 8]);
            const float4 b1 = *(const float4*)(&Bs[kk][tx * 8 + 4]);
            const float av[8] = { a0.x, a0.y, a0.z, a0.w, a1.x, a1.y, a1.z, a1.w };
            const float bv[8] = { b0.x, b0.y, b0.z, b0.w, b1.x, b1.y, b1.z, b1.w };
#pragma unroll
            for (int i = 0; i < 8; ++i)
#pragma unroll
                for (int j = 0; j < 8; ++j)
                    acc[i][j] = fmaf(av[i], bv[j], acc[i][j]);
        }
        __syncthreads();
    }

    float bv8[8];
#pragma unroll
    for (int j = 0; j < 8; ++j) bv8[j] = bias[bn + tx * 8 + j];
#pragma unroll
    for (int i = 0; i < 8; ++i) {
        float4 o0, o1;
        o0.x = acc[i][0] + bv8[0]; o0.y = acc[i][1] + bv8[1];
        o0.z = acc[i][2] + bv8[2]; o0.w = acc[i][3] + bv8[3];
        o1.x = acc[i][4] + bv8[4]; o1.y = acc[i][5] + bv8[5];
        o1.z = acc[i][6] + bv8[6]; o1.w = acc[i][7] + bv8[7];
        const size_t off = (size_t)(bm + ty * 8 + i) * NSAE + bn + tx * 8;
        *(float4*)(pre + off) = o0;
        *(float4*)(pre + off + 4) = o1;
    }
}

// ---------------- per-row radix top-64 + z scatter ----------------
// one block per row; exact threshold via 4x8-bit MSB radix passes over
// monotonic keys; ties broken toward smaller index (matches jax top_k set).
__global__ __launch_bounds__(256) void topk_kernel(
    const float* __restrict__ pre,
    int* __restrict__ tk_idx, float* __restrict__ tk_val,
    float* __restrict__ z)
{
    __shared__ unsigned hist[256];
    __shared__ int sel[NK];
    __shared__ int ties[256];
    __shared__ unsigned sh_prefix, sh_want, sh_cnt, sh_tiecnt;

    const int b = blockIdx.x;
    const int tid = threadIdx.x;
    const float* row = pre + (size_t)b * NSAE;
    float* zrow = z + (size_t)b * NSAE;

    // zero this row of z (poison-proof; scatter overwrites below)
    for (int i = tid * 4; i < NSAE; i += 256 * 4)
        *(float4*)(zrow + i) = make_float4(0.f, 0.f, 0.f, 0.f);

    if (tid == 0) { sh_prefix = 0u; sh_want = NK; sh_cnt = 0u; sh_tiecnt = 0u; }
    __syncthreads();

    for (int pass = 0; pass < 4; ++pass) {
        const int shift = 24 - pass * 8;
        const unsigned mask = (pass == 0) ? 0u : (0xFFFFFFFFu << (shift + 8));
        hist[tid] = 0u;
        __syncthreads();
        const unsigned pfx = sh_prefix;
        for (int i = tid; i < NSAE; i += 256) {
            const unsigned k = f2key(row[i]);
            if ((k & mask) == pfx) atomicAdd(&hist[(k >> shift) & 0xFFu], 1u);
        }
        __syncthreads();
        if (tid == 0) {
            const unsigned want = sh_want;
            unsigned cum = 0u;
            int bsel = 0;
            for (int bin = 255; bin >= 0; --bin) {
                const unsigned c = hist[bin];
                if (cum + c >= want) { bsel = bin; break; }
                cum += c;
            }
            sh_prefix |= ((unsigned)bsel << shift);
            sh_want = want - cum;
        }
        __syncthreads();
    }

    const unsigned T = sh_prefix;   // key of 64th-largest
    for (int i = tid; i < NSAE; i += 256) {
        const unsigned k = f2key(row[i]);
        if (k > T) {
            const unsigned s = atomicAdd(&sh_cnt, 1u);
            sel[s] = i;
        } else if (k == T) {
            const unsigned s = atomicAdd(&sh_tiecnt, 1u);
            if (s < 256u) ties[s] = i;
        }
    }
    __syncthreads();
    if (tid == 0) {
        const unsigned tc = sh_tiecnt;
        const int n = (int)(tc < 256u ? tc : 256u);
        for (int a = 1; a < n; ++a) {           // tiny insertion sort
            const int v = ties[a]; int c = a;
            while (c > 0 && ties[c - 1] > v) { ties[c] = ties[c - 1]; --c; }
            ties[c] = v;
        }
        const int base = (int)sh_cnt;
        const int want = (int)sh_want;
        for (int j = 0; j < want && j < n; ++j) sel[base + j] = ties[j];
    }
    __syncthreads();
    if (tid < NK) {
        const int myi = sel[tid];
        int rank = 0;                            // canonical (ascending-idx) order
#pragma unroll 1
        for (int j = 0; j < NK; ++j) rank += (sel[j] < myi) ? 1 : 0;
        const float v = fmaxf(row[myi], 0.f);    // relu
        tk_idx[b * NK + rank] = myi;
        tk_val[b * NK + rank] = v;
        zrow[myi] = v;
    }
}

// ---------------- inverse permutation ----------------
__global__ __launch_bounds__(256) void invperm_kernel(
    const int* __restrict__ perm, int* __restrict__ ipos)
{
    const int i = blockIdx.x * 256 + threadIdx.x;   // t*NSAE + p
    if (i < NT * NSAE) {
        const int t = i >> 14;
        const int p = i & (NSAE - 1);
        ipos[t * NSAE + perm[i]] = p;
    }
}

// ---------------- sparse decode + SSE partials ----------------
// one block per (b,t); both decoders; branch on p<PFX0 is wave-uniform.
__global__ __launch_bounds__(256) void decode_kernel(
    const float* __restrict__ x,
    const int* __restrict__ tk_idx, const float* __restrict__ tk_val,
    const int* __restrict__ ipos,
    const float* __restrict__ Wd0, const float* __restrict__ bd0,
    const float* __restrict__ Wd1, const float* __restrict__ bd1,
    float* __restrict__ xhat, float* __restrict__ part0, float* __restrict__ part1)
{
    const int bt = blockIdx.x;
    const int b = bt >> 2;
    const int t = bt & 3;
    const int tid = threadIdx.x;

    __shared__ int s_p[NK];
    __shared__ float s_v[NK];
    if (tid < NK) {
        const int s = tk_idx[b * NK + tid];
        s_v[tid] = tk_val[b * NK + tid];
        s_p[tid] = ipos[t * NSAE + s];
    }
    __syncthreads();

    float acc0[3], acc1[3];
#pragma unroll
    for (int r = 0; r < 3; ++r) {
        const int d = tid + 256 * r;
        acc0[r] = bd0[t * NDIN + d];
        acc1[r] = bd1[t * NDIN + d];
    }
    for (int j = 0; j < NK; ++j) {
        const int p = s_p[j];
        const float v = s_v[j];
        const float* w1 = Wd1 + ((size_t)p * NT + t) * NDIN;
#pragma unroll
        for (int r = 0; r < 3; ++r) acc1[r] = fmaf(v, w1[tid + 256 * r], acc1[r]);
        if (p < PFX0) {
            const float* w0 = Wd0 + ((size_t)p * NT + t) * NDIN;
#pragma unroll
            for (int r = 0; r < 3; ++r) acc0[r] = fmaf(v, w0[tid + 256 * r], acc0[r]);
        }
    }

    float e0 = 0.f, e1 = 0.f;
#pragma unroll
    for (int r = 0; r < 3; ++r) {
        const int d = tid + 256 * r;
        const float xv = x[(size_t)bt * NDIN + d];
        const float d0 = acc0[r] - xv;
        const float d1 = acc1[r] - xv;
        e0 = fmaf(d0, d0, e0);
        e1 = fmaf(d1, d1, e1);
        xhat[(size_t)bt * NDIN + d] = acc1[r];
    }

    __shared__ float r0[256];
    __shared__ float r1[256];
    r0[tid] = e0; r1[tid] = e1;
    __syncthreads();
    for (int w = 128; w > 0; w >>= 1) {
        if (tid < w) { r0[tid] += r0[tid + w]; r1[tid] += r1[tid + w]; }
        __syncthreads();
    }
    if (tid == 0) { part0[bt] = r0[0]; part1[bt] = r1[0]; }
}

// ---------------- final deterministic loss reduce ----------------
__global__ __launch_bounds__(256) void reduce_kernel(
    const float* __restrict__ part0, const float* __restrict__ part1,
    float* __restrict__ out_total)
{
    __shared__ double red[256];
    const int tid = threadIdx.x;
    double s = 0.0;
    for (int i = tid; i < NB * NT; i += 256)
        s += (double)part0[i] + (double)part1[i];
    red[tid] = s;
    __syncthreads();
    for (int w = 128; w > 0; w >>= 1) {
        if (tid < w) red[tid] += red[tid + w];
        __syncthreads();
    }
    // total = (sum_t mean_b sse0 + sum_t mean_b sse1) / (T*2)
    if (tid == 0) out_total[0] = (float)(red[0] / ((double)NB * (double)(NT * 2)));
}

extern "C" void kernel_launch(void* const* d_in, const int* in_sizes, int n_in,
                              void* d_out, int out_size, void* d_ws, size_t ws_size,
                              hipStream_t stream)
{
    const float* x     = (const float*)d_in[0];
    const float* W_enc = (const float*)d_in[1];
    const float* b_enc = (const float*)d_in[2];
    const float* Wd0   = (const float*)d_in[3];
    const float* bd0   = (const float*)d_in[4];
    const float* Wd1   = (const float*)d_in[5];
    const float* bd1   = (const float*)d_in[6];
    const int*   perm  = (const int*)d_in[7];

    float* out       = (float*)d_out;
    float* out_total = out;
    float* out_xhat  = out + 1;
    float* out_z     = out + 1 + (size_t)NB * NT * NDIN;

    char* ws = (char*)d_ws;
    size_t off = 0;
    float* pre    = (float*)(ws + off); off += (size_t)NB * NSAE * sizeof(float);
    int*   tk_idx = (int*)(ws + off);   off += (size_t)NB * NK * sizeof(int);
    float* tk_val = (float*)(ws + off); off += (size_t)NB * NK * sizeof(float);
    int*   ipos   = (int*)(ws + off);   off += (size_t)NT * NSAE * sizeof(int);
    float* part0  = (float*)(ws + off); off += (size_t)NB * NT * sizeof(float);
    float* part1  = (float*)(ws + off);

    gemm_pre_kernel<<<dim3(NSAE / 128, NB / 128), 256, 0, stream>>>(x, W_enc, b_enc, pre);
    invperm_kernel<<<(NT * NSAE) / 256, 256, 0, stream>>>(perm, ipos);
    topk_kernel<<<NB, 256, 0, stream>>>(pre, tk_idx, tk_val, out_z);
    decode_kernel<<<NB * NT, 256, 0, stream>>>(x, tk_idx, tk_val, ipos,
                                               Wd0, bd0, Wd1, bd1,
                                               out_xhat, part0, part1);
    reduce_kernel<<<1, 256, 0, stream>>>(part0, part1, out_total);
}

// Round 4
// 742.818 us; speedup vs baseline: 2.0341x; 2.0341x over previous
//
// R2: encoder GEMM via emulated-f32 (f16 2-way split, 3 MFMAs, dual f32 acc).
// pipeline: conv_a (x -> hi/lo f16) + conv_bt (W_enc -> transposed hi/lo f16)
//           -> mfma gemm (128x128 tile, m97 structure, swizzled LDS)
//           -> radix top64 -> invperm -> sparse decode -> reduce.
// Fallback to R1 f32 GEMM if ws_size < ~282MB.
#include <hip/hip_runtime.h>
#include <hip/hip_bf16.h>
#include <stdint.h>

#define NB    1024
#define NT    4
#define NDIN  768
#define NSAE  16384
#define NK    64
#define KDIM  3072
#define PFX0  8192
#define BKS   32
#define KSTEPS (KDIM / BKS)

typedef _Float16 f16x8 __attribute__((ext_vector_type(8)));
typedef _Float16 f16x4 __attribute__((ext_vector_type(4)));
typedef float    f32x4 __attribute__((ext_vector_type(4)));

__device__ __forceinline__ unsigned f2key(float f) {
    union { float f; unsigned u; } cv; cv.f = f;
    unsigned u = cv.u;
    return u ^ ((unsigned)((int)u >> 31) | 0x80000000u);  // monotonic float->uint
}

__device__ __forceinline__ void ld16(const void* g, void* l) {
    __builtin_amdgcn_global_load_lds(
        (const __attribute__((address_space(1))) void*)g,
        (__attribute__((address_space(3))) void*)l, 16, 0, 0);
}

// ---------------- split conversions ----------------
// v*64 = hi + lo/4096, both f16-normal for our value ranges.
__global__ __launch_bounds__(256) void conv_a_kernel(
    const float* __restrict__ A, _Float16* __restrict__ Ah, _Float16* __restrict__ Al)
{
    const size_t i = (size_t)(blockIdx.x * 256 + threadIdx.x) * 4;
    const float4 v = *(const float4*)(A + i);
    const float vv[4] = { v.x, v.y, v.z, v.w };
    f16x4 h, l;
#pragma unroll
    for (int j = 0; j < 4; ++j) {
        const float sv = vv[j] * 64.f;
        const _Float16 hh = (_Float16)sv;
        h[j] = hh;
        l[j] = (_Float16)((sv - (float)hh) * 4096.f);
    }
    *(f16x4*)(Ah + i) = h;
    *(f16x4*)(Al + i) = l;
}

// W_enc (K=3072, N=16384) row-major -> transposed [N][K] hi/lo f16 arrays.
__global__ __launch_bounds__(256) void conv_bt_kernel(
    const float* __restrict__ B, _Float16* __restrict__ Bh, _Float16* __restrict__ Bl)
{
    __shared__ float ts[64][65];
    const int n0 = blockIdx.x * 64;
    const int k0 = blockIdx.y * 64;
    const int tid = threadIdx.x;
#pragma unroll
    for (int i = 0; i < 4; ++i) {
        const int r = (tid >> 4) + i * 16;
        const int c = (tid & 15) * 4;
        const float4 v = *(const float4*)(B + (size_t)(k0 + r) * NSAE + n0 + c);
        ts[r][c] = v.x; ts[r][c + 1] = v.y; ts[r][c + 2] = v.z; ts[r][c + 3] = v.w;
    }
    __syncthreads();
    const int nl = tid >> 2;
    const int kc = (tid & 3) * 16;
    f16x8 h0{}, h1{}, l0{}, l1{};
#pragma unroll
    for (int j = 0; j < 8; ++j) {
        const float sv = ts[kc + j][nl] * 64.f;
        const _Float16 hh = (_Float16)sv;
        h0[j] = hh;
        l0[j] = (_Float16)((sv - (float)hh) * 4096.f);
    }
#pragma unroll
    for (int j = 0; j < 8; ++j) {
        const float sv = ts[kc + 8 + j][nl] * 64.f;
        const _Float16 hh = (_Float16)sv;
        h1[j] = hh;
        l1[j] = (_Float16)((sv - (float)hh) * 4096.f);
    }
    const size_t ob = (size_t)(n0 + nl) * KDIM + k0 + kc;
    *(f16x8*)(Bh + ob)     = h0;
    *(f16x8*)(Bh + ob + 8) = h1;
    *(f16x8*)(Bl + ob)     = l0;
    *(f16x8*)(Bl + ob + 8) = l1;
}

// ---------------- MFMA GEMM: pre = (A @ B) + bias, emulated f32 ----------------
// 128x128 tile, BK=32, 4 waves (2x2) of 64x64, 16x16x32_f16 frags 4x4/wave.
// LDS slot-swizzle: slot ^= (row>>1)&3 applied on global SOURCE (staging) and
// on ds_read (both-sides, G21); frag k stays 8-contiguous within a 16B slot.
__global__ __launch_bounds__(256, 2) void gemm_f16split_kernel(
    const _Float16* __restrict__ Ah, const _Float16* __restrict__ Al,
    const _Float16* __restrict__ Bh, const _Float16* __restrict__ Bl,
    const float* __restrict__ bias, float* __restrict__ pre)
{
    __shared__ _Float16 sAh[128 * BKS], sAl[128 * BKS], sBh[128 * BKS], sBl[128 * BKS];
    const int tid = threadIdx.x;
    const int lane = tid & 63;
    const int wid = tid >> 6;
    const int wm = wid >> 1;
    const int wn = wid & 1;
    const int m0 = blockIdx.x * 128;
    const int n0 = blockIdx.y * 128;

    // staging: 2 rounds x 256 thr x 16B per array; LDS dest is linear,
    // global source carries the inverse swizzle.
    const int row0 = tid >> 2;        // local row 0..63
    const int row1 = 64 + row0;       // 64..127
    const int slot = tid & 3;
    const int sw0 = slot ^ ((row0 >> 1) & 3);
    const int sw1 = slot ^ ((row1 >> 1) & 3);
    const size_t offA0 = (size_t)(m0 + row0) * KDIM + sw0 * 8;
    const size_t offA1 = (size_t)(m0 + row1) * KDIM + sw1 * 8;
    const size_t offB0 = (size_t)(n0 + row0) * KDIM + sw0 * 8;
    const size_t offB1 = (size_t)(n0 + row1) * KDIM + sw1 * 8;
    const int ldsoff0 = tid * 8;         // f16 elements
    const int ldsoff1 = 2048 + tid * 8;

    // fragment read addressing (swizzled): slot' = qw ^ ((rl>>1)&3) is
    // frag-invariant because wave/frag row offsets are multiples of 8 rows.
    const int rl = lane & 15;
    const int qw = lane >> 4;
    const int ksl = (qw ^ ((rl >> 1) & 3)) * 8;
    const int afr = (wm * 64 + rl) * BKS + ksl;
    const int bfr = (wn * 64 + rl) * BKS + ksl;

    f32x4 acc1[4][4], acc2[4][4];
#pragma unroll
    for (int mi = 0; mi < 4; ++mi)
#pragma unroll
        for (int ni = 0; ni < 4; ++ni) {
            acc1[mi][ni] = (f32x4){0.f, 0.f, 0.f, 0.f};
            acc2[mi][ni] = (f32x4){0.f, 0.f, 0.f, 0.f};
        }

    for (int kt = 0; kt < KSTEPS; ++kt) {
        const int k0 = kt * BKS;
        ld16(Ah + offA0 + k0, sAh + ldsoff0);
        ld16(Ah + offA1 + k0, sAh + ldsoff1);
        ld16(Al + offA0 + k0, sAl + ldsoff0);
        ld16(Al + offA1 + k0, sAl + ldsoff1);
        ld16(Bh + offB0 + k0, sBh + ldsoff0);
        ld16(Bh + offB1 + k0, sBh + ldsoff1);
        ld16(Bl + offB0 + k0, sBl + ldsoff0);
        ld16(Bl + offB1 + k0, sBl + ldsoff1);
        __syncthreads();

        f16x8 ah[4], al[4], bh[4], bl[4];
#pragma unroll
        for (int i = 0; i < 4; ++i) {
            ah[i] = *(const f16x8*)(sAh + afr + i * (16 * BKS));
            al[i] = *(const f16x8*)(sAl + afr + i * (16 * BKS));
            bh[i] = *(const f16x8*)(sBh + bfr + i * (16 * BKS));
            bl[i] = *(const f16x8*)(sBl + bfr + i * (16 * BKS));
        }
#pragma unroll
        for (int mi = 0; mi < 4; ++mi)
#pragma unroll
            for (int ni = 0; ni < 4; ++ni) {
                acc1[mi][ni] = __builtin_amdgcn_mfma_f32_16x16x32_f16(ah[mi], bh[ni], acc1[mi][ni], 0, 0, 0);
                acc2[mi][ni] = __builtin_amdgcn_mfma_f32_16x16x32_f16(ah[mi], bl[ni], acc2[mi][ni], 0, 0, 0);
                acc2[mi][ni] = __builtin_amdgcn_mfma_f32_16x16x32_f16(al[mi], bh[ni], acc2[mi][ni], 0, 0, 0);
            }
        __syncthreads();
    }

    // epilogue: pre = acc1*2^-12 + acc2*2^-24 + bias
    const float c12 = 1.0f / 4096.0f;
    const float c24 = 1.0f / 16777216.0f;
    float bv[4];
#pragma unroll
    for (int ni = 0; ni < 4; ++ni) bv[ni] = bias[n0 + wn * 64 + ni * 16 + rl];
#pragma unroll
    for (int mi = 0; mi < 4; ++mi)
#pragma unroll
        for (int ni = 0; ni < 4; ++ni)
#pragma unroll
            for (int r = 0; r < 4; ++r) {
                const int row = m0 + wm * 64 + mi * 16 + qw * 4 + r;
                const int col = n0 + wn * 64 + ni * 16 + rl;
                pre[(size_t)row * NSAE + col] =
                    acc1[mi][ni][r] * c12 + acc2[mi][ni][r] * c24 + bv[ni];
            }
}

// ---------------- f32 fallback GEMM (R1, known-good) ----------------
__global__ __launch_bounds__(256) void gemm_pre_kernel(
    const float* __restrict__ A, const float* __restrict__ Bm,
    const float* __restrict__ bias, float* __restrict__ pre)
{
    __shared__ float As[16][128];
    __shared__ float Bs[16][128];
    const int bn = blockIdx.x * 128;
    const int bm = blockIdx.y * 128;
    const int tid = threadIdx.x;
    const int tx = tid & 15;
    const int ty = tid >> 4;

    float acc[8][8];
#pragma unroll
    for (int i = 0; i < 8; ++i)
#pragma unroll
        for (int j = 0; j < 8; ++j) acc[i][j] = 0.f;

    for (int k0 = 0; k0 < KDIM; k0 += 16) {
#pragma unroll
        for (int i = 0; i < 2; ++i) {
            const int idx = i * 256 + tid;
            const int r = idx >> 2;
            const int c = (idx & 3) << 2;
            const float4 v = *(const float4*)(A + (size_t)(bm + r) * KDIM + (k0 + c));
            As[c + 0][r] = v.x; As[c + 1][r] = v.y;
            As[c + 2][r] = v.z; As[c + 3][r] = v.w;
        }
#pragma unroll
        for (int i = 0; i < 2; ++i) {
            const int idx = i * 256 + tid;
            const int r = idx >> 5;
            const int c = (idx & 31) << 2;
            *(float4*)(&Bs[r][c]) = *(const float4*)(Bm + (size_t)(k0 + r) * NSAE + (bn + c));
        }
        __syncthreads();
#pragma unroll
        for (int kk = 0; kk < 16; ++kk) {
            const float4 a0 = *(const float4*)(&As[kk][ty * 8]);
            const float4 a1 = *(const float4*)(&As[kk][ty * 8 + 4]);
            const float4 b0 = *(const float4*)(&Bs[kk][tx * 8]);
            const float4 b1 = *(const float4*)(&Bs[kk][tx * 8 + 4]);
            const float av[8] = { a0.x, a0.y, a0.z, a0.w, a1.x, a1.y, a1.z, a1.w };
            const float bv[8] = { b0.x, b0.y, b0.z, b0.w, b1.x, b1.y, b1.z, b1.w };
#pragma unroll
            for (int i = 0; i < 8; ++i)
#pragma unroll
                for (int j = 0; j < 8; ++j)
                    acc[i][j] = fmaf(av[i], bv[j], acc[i][j]);
        }
        __syncthreads();
    }

    float bv8[8];
#pragma unroll
    for (int j = 0; j < 8; ++j) bv8[j] = bias[bn + tx * 8 + j];
#pragma unroll
    for (int i = 0; i < 8; ++i) {
        float4 o0, o1;
        o0.x = acc[i][0] + bv8[0]; o0.y = acc[i][1] + bv8[1];
        o0.z = acc[i][2] + bv8[2]; o0.w = acc[i][3] + bv8[3];
        o1.x = acc[i][4] + bv8[4]; o1.y = acc[i][5] + bv8[5];
        o1.z = acc[i][6] + bv8[6]; o1.w = acc[i][7] + bv8[7];
        const size_t off = (size_t)(bm + ty * 8 + i) * NSAE + bn + tx * 8;
        *(float4*)(pre + off) = o0;
        *(float4*)(pre + off + 4) = o1;
    }
}

// ---------------- per-row radix top-64 + z scatter ----------------
__global__ __launch_bounds__(256) void topk_kernel(
    const float* __restrict__ pre,
    int* __restrict__ tk_idx, float* __restrict__ tk_val,
    float* __restrict__ z)
{
    __shared__ unsigned hist[256];
    __shared__ int sel[NK];
    __shared__ int ties[256];
    __shared__ unsigned sh_prefix, sh_want, sh_cnt, sh_tiecnt;

    const int b = blockIdx.x;
    const int tid = threadIdx.x;
    const float* row = pre + (size_t)b * NSAE;
    float* zrow = z + (size_t)b * NSAE;

    for (int i = tid * 4; i < NSAE; i += 256 * 4)
        *(float4*)(zrow + i) = make_float4(0.f, 0.f, 0.f, 0.f);

    if (tid == 0) { sh_prefix = 0u; sh_want = NK; sh_cnt = 0u; sh_tiecnt = 0u; }
    __syncthreads();

    for (int pass = 0; pass < 4; ++pass) {
        const int shift = 24 - pass * 8;
        const unsigned mask = (pass == 0) ? 0u : (0xFFFFFFFFu << (shift + 8));
        hist[tid] = 0u;
        __syncthreads();
        const unsigned pfx = sh_prefix;
        for (int i = tid; i < NSAE; i += 256) {
            const unsigned k = f2key(row[i]);
            if ((k & mask) == pfx) atomicAdd(&hist[(k >> shift) & 0xFFu], 1u);
        }
        __syncthreads();
        if (tid == 0) {
            const unsigned want = sh_want;
            unsigned cum = 0u;
            int bsel = 0;
            for (int bin = 255; bin >= 0; --bin) {
                const unsigned c = hist[bin];
                if (cum + c >= want) { bsel = bin; break; }
                cum += c;
            }
            sh_prefix |= ((unsigned)bsel << shift);
            sh_want = want - cum;
        }
        __syncthreads();
    }

    const unsigned T = sh_prefix;
    for (int i = tid; i < NSAE; i += 256) {
        const unsigned k = f2key(row[i]);
        if (k > T) {
            const unsigned s = atomicAdd(&sh_cnt, 1u);
            sel[s] = i;
        } else if (k == T) {
            const unsigned s = atomicAdd(&sh_tiecnt, 1u);
            if (s < 256u) ties[s] = i;
        }
    }
    __syncthreads();
    if (tid == 0) {
        const unsigned tc = sh_tiecnt;
        const int n = (int)(tc < 256u ? tc : 256u);
        for (int a = 1; a < n; ++a) {
            const int v = ties[a]; int c = a;
            while (c > 0 && ties[c - 1] > v) { ties[c] = ties[c - 1]; --c; }
            ties[c] = v;
        }
        const int base = (int)sh_cnt;
        const int want = (int)sh_want;
        for (int j = 0; j < want && j < n; ++j) sel[base + j] = ties[j];
    }
    __syncthreads();
    if (tid < NK) {
        const int myi = sel[tid];
        int rank = 0;
#pragma unroll 1
        for (int j = 0; j < NK; ++j) rank += (sel[j] < myi) ? 1 : 0;
        const float v = fmaxf(row[myi], 0.f);
        tk_idx[b * NK + rank] = myi;
        tk_val[b * NK + rank] = v;
        zrow[myi] = v;
    }
}

// ---------------- inverse permutation ----------------
__global__ __launch_bounds__(256) void invperm_kernel(
    const int* __restrict__ perm, int* __restrict__ ipos)
{
    const int i = blockIdx.x * 256 + threadIdx.x;
    if (i < NT * NSAE) {
        const int t = i >> 14;
        ipos[t * NSAE + perm[i]] = i & (NSAE - 1);
    }
}

// ---------------- sparse decode + SSE partials ----------------
__global__ __launch_bounds__(256) void decode_kernel(
    const float* __restrict__ x,
    const int* __restrict__ tk_idx, const float* __restrict__ tk_val,
    const int* __restrict__ ipos,
    const float* __restrict__ Wd0, const float* __restrict__ bd0,
    const float* __restrict__ Wd1, const float* __restrict__ bd1,
    float* __restrict__ xhat, float* __restrict__ part0, float* __restrict__ part1)
{
    const int bt = blockIdx.x;
    const int b = bt >> 2;
    const int t = bt & 3;
    const int tid = threadIdx.x;

    __shared__ int s_p[NK];
    __shared__ float s_v[NK];
    if (tid < NK) {
        const int s = tk_idx[b * NK + tid];
        s_v[tid] = tk_val[b * NK + tid];
        s_p[tid] = ipos[t * NSAE + s];
    }
    __syncthreads();

    float acc0[3], acc1[3];
#pragma unroll
    for (int r = 0; r < 3; ++r) {
        const int d = tid + 256 * r;
        acc0[r] = bd0[t * NDIN + d];
        acc1[r] = bd1[t * NDIN + d];
    }
    for (int j = 0; j < NK; ++j) {
        const int p = s_p[j];
        const float v = s_v[j];
        const float* w1 = Wd1 + ((size_t)p * NT + t) * NDIN;
#pragma unroll
        for (int r = 0; r < 3; ++r) acc1[r] = fmaf(v, w1[tid + 256 * r], acc1[r]);
        if (p < PFX0) {
            const float* w0 = Wd0 + ((size_t)p * NT + t) * NDIN;
#pragma unroll
            for (int r = 0; r < 3; ++r) acc0[r] = fmaf(v, w0[tid + 256 * r], acc0[r]);
        }
    }

    float e0 = 0.f, e1 = 0.f;
#pragma unroll
    for (int r = 0; r < 3; ++r) {
        const int d = tid + 256 * r;
        const float xv = x[(size_t)bt * NDIN + d];
        const float d0 = acc0[r] - xv;
        const float d1 = acc1[r] - xv;
        e0 = fmaf(d0, d0, e0);
        e1 = fmaf(d1, d1, e1);
        xhat[(size_t)bt * NDIN + d] = acc1[r];
    }

    __shared__ float r0[256];
    __shared__ float r1[256];
    r0[tid] = e0; r1[tid] = e1;
    __syncthreads();
    for (int w = 128; w > 0; w >>= 1) {
        if (tid < w) { r0[tid] += r0[tid + w]; r1[tid] += r1[tid + w]; }
        __syncthreads();
    }
    if (tid == 0) { part0[bt] = r0[0]; part1[bt] = r1[0]; }
}

// ---------------- final deterministic loss reduce ----------------
__global__ __launch_bounds__(256) void reduce_kernel(
    const float* __restrict__ part0, const float* __restrict__ part1,
    float* __restrict__ out_total)
{
    __shared__ double red[256];
    const int tid = threadIdx.x;
    double s = 0.0;
    for (int i = tid; i < NB * NT; i += 256)
        s += (double)part0[i] + (double)part1[i];
    red[tid] = s;
    __syncthreads();
    for (int w = 128; w > 0; w >>= 1) {
        if (tid < w) red[tid] += red[tid + w];
        __syncthreads();
    }
    if (tid == 0) out_total[0] = (float)(red[0] / ((double)NB * (double)(NT * 2)));
}

extern "C" void kernel_launch(void* const* d_in, const int* in_sizes, int n_in,
                              void* d_out, int out_size, void* d_ws, size_t ws_size,
                              hipStream_t stream)
{
    const float* x     = (const float*)d_in[0];
    const float* W_enc = (const float*)d_in[1];
    const float* b_enc = (const float*)d_in[2];
    const float* Wd0   = (const float*)d_in[3];
    const float* bd0   = (const float*)d_in[4];
    const float* Wd1   = (const float*)d_in[5];
    const float* bd1   = (const float*)d_in[6];
    const int*   perm  = (const int*)d_in[7];

    float* out       = (float*)d_out;
    float* out_total = out;
    float* out_xhat  = out + 1;
    float* out_z     = out + 1 + (size_t)NB * NT * NDIN;

    char* ws = (char*)d_ws;
    size_t off = 0;
    float* pre = (float*)(ws + off); off += (size_t)NB * NSAE * sizeof(float);

    const size_t szA = (size_t)NB * KDIM * sizeof(_Float16);     // 6.29 MB
    const size_t szB = (size_t)NSAE * KDIM * sizeof(_Float16);   // 100.7 MB
    _Float16* Ah = (_Float16*)(ws + off); 
    _Float16* Al = (_Float16*)(ws + off + szA);
    _Float16* Bh = (_Float16*)(ws + off + 2 * szA);
    _Float16* Bl = (_Float16*)(ws + off + 2 * szA + szB);
    const size_t off_splits_end = off + 2 * szA + 2 * szB;

    const bool fast = (ws_size >= off_splits_end + ((size_t)NB * NK * 8 + (size_t)NT * NSAE * 4 + (size_t)NB * NT * 8));
    size_t tail = fast ? off_splits_end : off;
    int*   tk_idx = (int*)(ws + tail);   tail += (size_t)NB * NK * sizeof(int);
    float* tk_val = (float*)(ws + tail); tail += (size_t)NB * NK * sizeof(float);
    int*   ipos   = (int*)(ws + tail);   tail += (size_t)NT * NSAE * sizeof(int);
    float* part0  = (float*)(ws + tail); tail += (size_t)NB * NT * sizeof(float);
    float* part1  = (float*)(ws + tail);

    if (fast) {
        conv_a_kernel<<<(NB * KDIM) / (256 * 4), 256, 0, stream>>>(x, Ah, Al);
        conv_bt_kernel<<<dim3(NSAE / 64, KDIM / 64), 256, 0, stream>>>(W_enc, Bh, Bl);
        gemm_f16split_kernel<<<dim3(NB / 128, NSAE / 128), 256, 0, stream>>>(
            Ah, Al, Bh, Bl, b_enc, pre);
    } else {
        gemm_pre_kernel<<<dim3(NSAE / 128, NB / 128), 256, 0, stream>>>(x, W_enc, b_enc, pre);
    }
    invperm_kernel<<<(NT * NSAE) / 256, 256, 0, stream>>>(perm, ipos);
    topk_kernel<<<NB, 256, 0, stream>>>(pre, tk_idx, tk_val, out_z);
    decode_kernel<<<NB * NT, 256, 0, stream>>>(x, tk_idx, tk_val, ipos,
                                               Wd0, bd0, Wd1, bd1,
                                               out_xhat, part0, part1);
    reduce_kernel<<<1, 256, 0, stream>>>(part0, part1, out_total);
}

// Round 5
// 704.564 us; speedup vs baseline: 2.1446x; 1.0543x over previous
//
// R3: GEMM upgraded to T3/T4 pipeline (dbuf LDS, prefetch-before-compute,
// counted vmcnt(8)) + T1 XCD-chunked swizzle + T5 setprio.
// Interleaved hi/lo split layout: A2[m][vk], B2[n][vk], vk chunk c (64 f16)
// = [hi k=32c..32c+31][lo same]. LDS XOR-8 slot swizzle (G21 both-sides).
// Downstream (topk/invperm/decode/reduce) identical to R2.
#include <hip/hip_runtime.h>
#include <hip/hip_bf16.h>
#include <stdint.h>

#define NB    1024
#define NT    4
#define NDIN  768
#define NSAE  16384
#define NK    64
#define KDIM  3072
#define PFX0  8192
#define KT96  96          // K-steps of 32 real K (64 virtual)
#define VKD   6144        // virtual K per row (2*KDIM)

typedef _Float16 f16x8 __attribute__((ext_vector_type(8)));
typedef _Float16 f16x4 __attribute__((ext_vector_type(4)));
typedef float    f32x4 __attribute__((ext_vector_type(4)));

__device__ __forceinline__ unsigned f2key(float f) {
    union { float f; unsigned u; } cv; cv.f = f;
    unsigned u = cv.u;
    return u ^ ((unsigned)((int)u >> 31) | 0x80000000u);  // monotonic float->uint
}

__device__ __forceinline__ void ld16(const _Float16* g, _Float16* l) {
    __builtin_amdgcn_global_load_lds(
        (const __attribute__((address_space(1))) void*)g,
        (__attribute__((address_space(3))) void*)l, 16, 0, 0);
}

// ---------------- split conversions (interleaved layout) ----------------
// v*64 = hi + lo/4096. A2[m][c*64 + (k&31)] = hi, +32 = lo, c = k>>5.
__global__ __launch_bounds__(256) void conv_a_kernel(
    const float* __restrict__ A, _Float16* __restrict__ A2)
{
    const int gid = blockIdx.x * 256 + threadIdx.x;
    const int m = gid / (KDIM / 4);
    const int k = (gid % (KDIM / 4)) * 4;       // 4-aligned, stays in one 32-chunk
    const float4 v = *(const float4*)(A + (size_t)m * KDIM + k);
    const float vv[4] = { v.x, v.y, v.z, v.w };
    f16x4 h, l;
#pragma unroll
    for (int j = 0; j < 4; ++j) {
        const float sv = vv[j] * 64.f;
        const _Float16 hh = (_Float16)sv;
        h[j] = hh;
        l[j] = (_Float16)((sv - (float)hh) * 4096.f);
    }
    const size_t ob = (size_t)m * VKD + (k >> 5) * 64 + (k & 31);
    *(f16x4*)(A2 + ob)      = h;
    *(f16x4*)(A2 + ob + 32) = l;
}

// W_enc (K=3072, N=16384) row-major -> B2[n][vk] interleaved hi/lo.
__global__ __launch_bounds__(256) void conv_bt_kernel(
    const float* __restrict__ B, _Float16* __restrict__ B2)
{
    __shared__ float ts[64][65];
    const int n0 = blockIdx.x * 64;
    const int k0 = blockIdx.y * 64;
    const int tid = threadIdx.x;
#pragma unroll
    for (int i = 0; i < 4; ++i) {
        const int r = (tid >> 4) + i * 16;
        const int c = (tid & 15) * 4;
        const float4 v = *(const float4*)(B + (size_t)(k0 + r) * NSAE + n0 + c);
        ts[r][c] = v.x; ts[r][c + 1] = v.y; ts[r][c + 2] = v.z; ts[r][c + 3] = v.w;
    }
    __syncthreads();
    const int nl = tid >> 2;
    const int kc = (tid & 3) * 16;              // 0,16,32,48
    f16x8 h0{}, h1{}, l0{}, l1{};
#pragma unroll
    for (int j = 0; j < 8; ++j) {
        const float sv = ts[kc + j][nl] * 64.f;
        const _Float16 hh = (_Float16)sv;
        h0[j] = hh;
        l0[j] = (_Float16)((sv - (float)hh) * 4096.f);
    }
#pragma unroll
    for (int j = 0; j < 8; ++j) {
        const float sv = ts[kc + 8 + j][nl] * 64.f;
        const _Float16 hh = (_Float16)sv;
        h1[j] = hh;
        l1[j] = (_Float16)((sv - (float)hh) * 4096.f);
    }
    // chunk base for real k = k0+kc; within-chunk offset kc&31 in {0,16}
    const size_t ob = (size_t)(n0 + nl) * VKD + ((k0 + kc) >> 5) * 64 + (kc & 31);
    *(f16x8*)(B2 + ob)      = h0;
    *(f16x8*)(B2 + ob + 8)  = h1;
    *(f16x8*)(B2 + ob + 32) = l0;
    *(f16x8*)(B2 + ob + 40) = l1;
}

// ---------------- MFMA GEMM: pre = (A @ B) + bias, emulated f32 ----------------
// 128x128 tile, 4 waves (2x2), dbuf LDS [2][128][64] f16 per matrix (64KB).
// Per K-step: STAGE(next buf) -> vmcnt(8) -> barrier -> ds_read 16x b128 ->
// lgkmcnt(0) -> barrier -> setprio(1) 48 MFMA. Counted vmcnt keeps 8 loads
// in flight across barriers (T4). XOR-8 slot swizzle, inverse on source.
__global__ __launch_bounds__(256, 2) void gemm_f16split_kernel(
    const _Float16* __restrict__ A2, const _Float16* __restrict__ B2,
    const float* __restrict__ bias, float* __restrict__ pre)
{
    __shared__ _Float16 sA[2 * 128 * 64];
    __shared__ _Float16 sB[2 * 128 * 64];
    const int tid = threadIdx.x;
    const int lane = tid & 63;
    const int wid = tid >> 6;
    const int wm = wid >> 1;
    const int wn = wid & 1;

    // T1: chunked XCD swizzle. XCD x (= bid%8) gets n-panels x*16..x*16+15,
    // all 8 m-blocks each -> B-panel L2 reuse across its co-resident blocks.
    const int bid = blockIdx.x;
    const int swz = (bid & 7) * 128 + (bid >> 3);
    const int m0 = (swz & 7) * 128;
    const int n0 = (swz >> 3) * 128;

    // staging: 4 chunks/thread/matrix; LDS dest linear (= base + lane*16),
    // global source carries inverse swizzle (G21).
    const _Float16* pa[4]; const _Float16* pb[4];
    _Float16* da[4]; _Float16* db[4];
#pragma unroll
    for (int r = 0; r < 4; ++r) {
        const int d = tid + r * 256;
        const int row = d >> 3;
        const int ls = (d & 7) ^ (row & 7);     // logical slot at this dest
        pa[r] = A2 + (size_t)(m0 + row) * VKD + ls * 8;
        pb[r] = B2 + (size_t)(n0 + row) * VKD + ls * 8;
        da[r] = sA + d * 8;
        db[r] = sB + d * 8;
    }

    // fragment read offsets (swizzled): slot' = (4h+qw) ^ (rl&7)
    const int rl = lane & 15;
    const int qw = lane >> 4;
    const int aoff0 = ((0 + qw) ^ (rl & 7)) * 8 + rl * 64;   // hi half
    const int aoff1 = ((4 + qw) ^ (rl & 7)) * 8 + rl * 64;   // lo half

    f32x4 acc1[4][4], acc2[4][4];
#pragma unroll
    for (int mi = 0; mi < 4; ++mi)
#pragma unroll
        for (int ni = 0; ni < 4; ++ni) {
            acc1[mi][ni] = (f32x4){0.f, 0.f, 0.f, 0.f};
            acc2[mi][ni] = (f32x4){0.f, 0.f, 0.f, 0.f};
        }

    // prologue: stage tile 0 into buf 0
#pragma unroll
    for (int r = 0; r < 4; ++r) { ld16(pa[r], da[r]); ld16(pb[r], db[r]); }

    for (int kt = 0; kt < KT96; ++kt) {
        const int cb = (kt & 1) ? 8192 : 0;
        const int nb = cb ^ 8192;
        if (kt + 1 < KT96) {
            const int ko = (kt + 1) * 64;
#pragma unroll
            for (int r = 0; r < 4; ++r) {
                ld16(pa[r] + ko, da[r] + nb);
                ld16(pb[r] + ko, db[r] + nb);
            }
            asm volatile("s_waitcnt vmcnt(8)" ::: "memory");  // cur tile done, 8 in flight
        } else {
            asm volatile("s_waitcnt vmcnt(0)" ::: "memory");
        }
        __builtin_amdgcn_sched_barrier(0);
        __builtin_amdgcn_s_barrier();            // stage-for-cur complete everywhere
        __builtin_amdgcn_sched_barrier(0);

        f16x8 af[4][2], bf[4][2];
#pragma unroll
        for (int i = 0; i < 4; ++i) {
            const int ra = cb + (wm * 64 + i * 16) * 64;
            const int rb = cb + (wn * 64 + i * 16) * 64;
            af[i][0] = *(const f16x8*)(sA + ra + aoff0);
            af[i][1] = *(const f16x8*)(sA + ra + aoff1);
            bf[i][0] = *(const f16x8*)(sB + rb + aoff0);
            bf[i][1] = *(const f16x8*)(sB + rb + aoff1);
        }
        asm volatile("s_waitcnt lgkmcnt(0)" ::: "memory");
        __builtin_amdgcn_sched_barrier(0);       // rule #18: pin MFMA below
        __builtin_amdgcn_s_barrier();            // all waves done reading cur buf

        __builtin_amdgcn_s_setprio(1);
#pragma unroll
        for (int mi = 0; mi < 4; ++mi)
#pragma unroll
            for (int ni = 0; ni < 4; ++ni) {
                acc1[mi][ni] = __builtin_amdgcn_mfma_f32_16x16x32_f16(af[mi][0], bf[ni][0], acc1[mi][ni], 0, 0, 0);
                acc2[mi][ni] = __builtin_amdgcn_mfma_f32_16x16x32_f16(af[mi][0], bf[ni][1], acc2[mi][ni], 0, 0, 0);
                acc2[mi][ni] = __builtin_amdgcn_mfma_f32_16x16x32_f16(af[mi][1], bf[ni][0], acc2[mi][ni], 0, 0, 0);
            }
        __builtin_amdgcn_s_setprio(0);
    }

    // epilogue: pre = acc1*2^-12 + acc2*2^-24 + bias
    const float c12 = 1.0f / 4096.0f;
    const float c24 = 1.0f / 16777216.0f;
    float bv[4];
#pragma unroll
    for (int ni = 0; ni < 4; ++ni) bv[ni] = bias[n0 + wn * 64 + ni * 16 + rl];
#pragma unroll
    for (int mi = 0; mi < 4; ++mi)
#pragma unroll
        for (int ni = 0; ni < 4; ++ni)
#pragma unroll
            for (int r = 0; r < 4; ++r) {
                const int row = m0 + wm * 64 + mi * 16 + qw * 4 + r;
                const int col = n0 + wn * 64 + ni * 16 + rl;
                pre[(size_t)row * NSAE + col] =
                    acc1[mi][ni][r] * c12 + acc2[mi][ni][r] * c24 + bv[ni];
            }
}

// ---------------- f32 fallback GEMM (R1, known-good) ----------------
__global__ __launch_bounds__(256) void gemm_pre_kernel(
    const float* __restrict__ A, const float* __restrict__ Bm,
    const float* __restrict__ bias, float* __restrict__ pre)
{
    __shared__ float As[16][128];
    __shared__ float Bs[16][128];
    const int bn = blockIdx.x * 128;
    const int bm = blockIdx.y * 128;
    const int tid = threadIdx.x;
    const int tx = tid & 15;
    const int ty = tid >> 4;

    float acc[8][8];
#pragma unroll
    for (int i = 0; i < 8; ++i)
#pragma unroll
        for (int j = 0; j < 8; ++j) acc[i][j] = 0.f;

    for (int k0 = 0; k0 < KDIM; k0 += 16) {
#pragma unroll
        for (int i = 0; i < 2; ++i) {
            const int idx = i * 256 + tid;
            const int r = idx >> 2;
            const int c = (idx & 3) << 2;
            const float4 v = *(const float4*)(A + (size_t)(bm + r) * KDIM + (k0 + c));
            As[c + 0][r] = v.x; As[c + 1][r] = v.y;
            As[c + 2][r] = v.z; As[c + 3][r] = v.w;
        }
#pragma unroll
        for (int i = 0; i < 2; ++i) {
            const int idx = i * 256 + tid;
            const int r = idx >> 5;
            const int c = (idx & 31) << 2;
            *(float4*)(&Bs[r][c]) = *(const float4*)(Bm + (size_t)(k0 + r) * NSAE + (bn + c));
        }
        __syncthreads();
#pragma unroll
        for (int kk = 0; kk < 16; ++kk) {
            const float4 a0 = *(const float4*)(&As[kk][ty * 8]);
            const float4 a1 = *(const float4*)(&As[kk][ty * 8 + 4]);
            const float4 b0 = *(const float4*)(&Bs[kk][tx * 8]);
            const float4 b1 = *(const float4*)(&Bs[kk][tx * 8 + 4]);
            const float av[8] = { a0.x, a0.y, a0.z, a0.w, a1.x, a1.y, a1.z, a1.w };
            const float bv[8] = { b0.x, b0.y, b0.z, b0.w, b1.x, b1.y, b1.z, b1.w };
#pragma unroll
            for (int i = 0; i < 8; ++i)
#pragma unroll
                for (int j = 0; j < 8; ++j)
                    acc[i][j] = fmaf(av[i], bv[j], acc[i][j]);
        }
        __syncthreads();
    }

    float bv8[8];
#pragma unroll
    for (int j = 0; j < 8; ++j) bv8[j] = bias[bn + tx * 8 + j];
#pragma unroll
    for (int i = 0; i < 8; ++i) {
        float4 o0, o1;
        o0.x = acc[i][0] + bv8[0]; o0.y = acc[i][1] + bv8[1];
        o0.z = acc[i][2] + bv8[2]; o0.w = acc[i][3] + bv8[3];
        o1.x = acc[i][4] + bv8[4]; o1.y = acc[i][5] + bv8[5];
        o1.z = acc[i][6] + bv8[6]; o1.w = acc[i][7] + bv8[7];
        const size_t off = (size_t)(bm + ty * 8 + i) * NSAE + bn + tx * 8;
        *(float4*)(pre + off) = o0;
        *(float4*)(pre + off + 4) = o1;
    }
}

// ---------------- per-row radix top-64 + z scatter ----------------
__global__ __launch_bounds__(256) void topk_kernel(
    const float* __restrict__ pre,
    int* __restrict__ tk_idx, float* __restrict__ tk_val,
    float* __restrict__ z)
{
    __shared__ unsigned hist[256];
    __shared__ int sel[NK];
    __shared__ int ties[256];
    __shared__ unsigned sh_prefix, sh_want, sh_cnt, sh_tiecnt;

    const int b = blockIdx.x;
    const int tid = threadIdx.x;
    const float* row = pre + (size_t)b * NSAE;
    float* zrow = z + (size_t)b * NSAE;

    for (int i = tid * 4; i < NSAE; i += 256 * 4)
        *(float4*)(zrow + i) = make_float4(0.f, 0.f, 0.f, 0.f);

    if (tid == 0) { sh_prefix = 0u; sh_want = NK; sh_cnt = 0u; sh_tiecnt = 0u; }
    __syncthreads();

    for (int pass = 0; pass < 4; ++pass) {
        const int shift = 24 - pass * 8;
        const unsigned mask = (pass == 0) ? 0u : (0xFFFFFFFFu << (shift + 8));
        hist[tid] = 0u;
        __syncthreads();
        const unsigned pfx = sh_prefix;
        for (int i = tid; i < NSAE; i += 256) {
            const unsigned k = f2key(row[i]);
            if ((k & mask) == pfx) atomicAdd(&hist[(k >> shift) & 0xFFu], 1u);
        }
        __syncthreads();
        if (tid == 0) {
            const unsigned want = sh_want;
            unsigned cum = 0u;
            int bsel = 0;
            for (int bin = 255; bin >= 0; --bin) {
                const unsigned c = hist[bin];
                if (cum + c >= want) { bsel = bin; break; }
                cum += c;
            }
            sh_prefix |= ((unsigned)bsel << shift);
            sh_want = want - cum;
        }
        __syncthreads();
    }

    const unsigned T = sh_prefix;
    for (int i = tid; i < NSAE; i += 256) {
        const unsigned k = f2key(row[i]);
        if (k > T) {
            const unsigned s = atomicAdd(&sh_cnt, 1u);
            sel[s] = i;
        } else if (k == T) {
            const unsigned s = atomicAdd(&sh_tiecnt, 1u);
            if (s < 256u) ties[s] = i;
        }
    }
    __syncthreads();
    if (tid == 0) {
        const unsigned tc = sh_tiecnt;
        const int n = (int)(tc < 256u ? tc : 256u);
        for (int a = 1; a < n; ++a) {
            const int v = ties[a]; int c = a;
            while (c > 0 && ties[c - 1] > v) { ties[c] = ties[c - 1]; --c; }
            ties[c] = v;
        }
        const int base = (int)sh_cnt;
        const int want = (int)sh_want;
        for (int j = 0; j < want && j < n; ++j) sel[base + j] = ties[j];
    }
    __syncthreads();
    if (tid < NK) {
        const int myi = sel[tid];
        int rank = 0;
#pragma unroll 1
        for (int j = 0; j < NK; ++j) rank += (sel[j] < myi) ? 1 : 0;
        const float v = fmaxf(row[myi], 0.f);
        tk_idx[b * NK + rank] = myi;
        tk_val[b * NK + rank] = v;
        zrow[myi] = v;
    }
}

// ---------------- inverse permutation ----------------
__global__ __launch_bounds__(256) void invperm_kernel(
    const int* __restrict__ perm, int* __restrict__ ipos)
{
    const int i = blockIdx.x * 256 + threadIdx.x;
    if (i < NT * NSAE) {
        const int t = i >> 14;
        ipos[t * NSAE + perm[i]] = i & (NSAE - 1);
    }
}

// ---------------- sparse decode + SSE partials ----------------
__global__ __launch_bounds__(256) void decode_kernel(
    const float* __restrict__ x,
    const int* __restrict__ tk_idx, const float* __restrict__ tk_val,
    const int* __restrict__ ipos,
    const float* __restrict__ Wd0, const float* __restrict__ bd0,
    const float* __restrict__ Wd1, const float* __restrict__ bd1,
    float* __restrict__ xhat, float* __restrict__ part0, float* __restrict__ part1)
{
    const int bt = blockIdx.x;
    const int b = bt >> 2;
    const int t = bt & 3;
    const int tid = threadIdx.x;

    __shared__ int s_p[NK];
    __shared__ float s_v[NK];
    if (tid < NK) {
        const int s = tk_idx[b * NK + tid];
        s_v[tid] = tk_val[b * NK + tid];
        s_p[tid] = ipos[t * NSAE + s];
    }
    __syncthreads();

    float acc0[3], acc1[3];
#pragma unroll
    for (int r = 0; r < 3; ++r) {
        const int d = tid + 256 * r;
        acc0[r] = bd0[t * NDIN + d];
        acc1[r] = bd1[t * NDIN + d];
    }
    for (int j = 0; j < NK; ++j) {
        const int p = s_p[j];
        const float v = s_v[j];
        const float* w1 = Wd1 + ((size_t)p * NT + t) * NDIN;
#pragma unroll
        for (int r = 0; r < 3; ++r) acc1[r] = fmaf(v, w1[tid + 256 * r], acc1[r]);
        if (p < PFX0) {
            const float* w0 = Wd0 + ((size_t)p * NT + t) * NDIN;
#pragma unroll
            for (int r = 0; r < 3; ++r) acc0[r] = fmaf(v, w0[tid + 256 * r], acc0[r]);
        }
    }

    float e0 = 0.f, e1 = 0.f;
#pragma unroll
    for (int r = 0; r < 3; ++r) {
        const int d = tid + 256 * r;
        const float xv = x[(size_t)bt * NDIN + d];
        const float d0 = acc0[r] - xv;
        const float d1 = acc1[r] - xv;
        e0 = fmaf(d0, d0, e0);
        e1 = fmaf(d1, d1, e1);
        xhat[(size_t)bt * NDIN + d] = acc1[r];
    }

    __shared__ float r0[256];
    __shared__ float r1[256];
    r0[tid] = e0; r1[tid] = e1;
    __syncthreads();
    for (int w = 128; w > 0; w >>= 1) {
        if (tid < w) { r0[tid] += r0[tid + w]; r1[tid] += r1[tid + w]; }
        __syncthreads();
    }
    if (tid == 0) { part0[bt] = r0[0]; part1[bt] = r1[0]; }
}

// ---------------- final deterministic loss reduce ----------------
__global__ __launch_bounds__(256) void reduce_kernel(
    const float* __restrict__ part0, const float* __restrict__ part1,
    float* __restrict__ out_total)
{
    __shared__ double red[256];
    const int tid = threadIdx.x;
    double s = 0.0;
    for (int i = tid; i < NB * NT; i += 256)
        s += (double)part0[i] + (double)part1[i];
    red[tid] = s;
    __syncthreads();
    for (int w = 128; w > 0; w >>= 1) {
        if (tid < w) red[tid] += red[tid + w];
        __syncthreads();
    }
    if (tid == 0) out_total[0] = (float)(red[0] / ((double)NB * (double)(NT * 2)));
}

extern "C" void kernel_launch(void* const* d_in, const int* in_sizes, int n_in,
                              void* d_out, int out_size, void* d_ws, size_t ws_size,
                              hipStream_t stream)
{
    const float* x     = (const float*)d_in[0];
    const float* W_enc = (const float*)d_in[1];
    const float* b_enc = (const float*)d_in[2];
    const float* Wd0   = (const float*)d_in[3];
    const float* bd0   = (const float*)d_in[4];
    const float* Wd1   = (const float*)d_in[5];
    const float* bd1   = (const float*)d_in[6];
    const int*   perm  = (const int*)d_in[7];

    float* out       = (float*)d_out;
    float* out_total = out;
    float* out_xhat  = out + 1;
    float* out_z     = out + 1 + (size_t)NB * NT * NDIN;

    char* ws = (char*)d_ws;
    size_t off = 0;
    float* pre = (float*)(ws + off); off += (size_t)NB * NSAE * sizeof(float);

    const size_t szA2 = (size_t)NB * VKD * sizeof(_Float16);     // 12.6 MB
    const size_t szB2 = (size_t)NSAE * VKD * sizeof(_Float16);   // 201.3 MB
    _Float16* A2 = (_Float16*)(ws + off);
    _Float16* B2 = (_Float16*)(ws + off + szA2);
    const size_t off_splits_end = off + szA2 + szB2;

    const bool fast = (ws_size >= off_splits_end +
        ((size_t)NB * NK * 8 + (size_t)NT * NSAE * 4 + (size_t)NB * NT * 8));
    size_t tail = fast ? off_splits_end : off;
    int*   tk_idx = (int*)(ws + tail);   tail += (size_t)NB * NK * sizeof(int);
    float* tk_val = (float*)(ws + tail); tail += (size_t)NB * NK * sizeof(float);
    int*   ipos   = (int*)(ws + tail);   tail += (size_t)NT * NSAE * sizeof(int);
    float* part0  = (float*)(ws + tail); tail += (size_t)NB * NT * sizeof(float);
    float* part1  = (float*)(ws + tail);

    if (fast) {
        conv_a_kernel<<<(NB * KDIM) / (256 * 4), 256, 0, stream>>>(x, A2);
        conv_bt_kernel<<<dim3(NSAE / 64, KDIM / 64), 256, 0, stream>>>(W_enc, B2);
        gemm_f16split_kernel<<<1024, 256, 0, stream>>>(A2, B2, b_enc, pre);
    } else {
        gemm_pre_kernel<<<dim3(NSAE / 128, NB / 128), 256, 0, stream>>>(x, W_enc, b_enc, pre);
    }
    invperm_kernel<<<(NT * NSAE) / 256, 256, 0, stream>>>(perm, ipos);
    topk_kernel<<<NB, 256, 0, stream>>>(pre, tk_idx, tk_val, out_z);
    decode_kernel<<<NB * NT, 256, 0, stream>>>(x, tk_idx, tk_val, ipos,
                                               Wd0, bd0, Wd1, bd1,
                                               out_xhat, part0, part1);
    reduce_kernel<<<1, 256, 0, stream>>>(part0, part1, out_total);
}

// Round 6
// 641.622 us; speedup vs baseline: 2.3549x; 1.0981x over previous
//
// R4: (1) GEMM K-loop lets compiler interleave ds_read with MFMA (no lgkm
//     full-drain); (2) topk holds row in registers, per-wave hists, zero
//     global re-reads; (3) conv_bt coalesced 256B-run writes.
// GEMM skeleton (dbuf, vmcnt(8), T1 chunked swizzle, XOR-8 LDS swizzle)
// unchanged from R3 (passed, absmax 0.03125).
#include <hip/hip_runtime.h>
#include <hip/hip_bf16.h>
#include <stdint.h>

#define NB    1024
#define NT    4
#define NDIN  768
#define NSAE  16384
#define NK    64
#define KDIM  3072
#define PFX0  8192
#define KT96  96          // K-steps of 32 real K (64 virtual)
#define VKD   6144        // virtual K per row (2*KDIM)

typedef _Float16 f16x8 __attribute__((ext_vector_type(8)));
typedef _Float16 f16x4 __attribute__((ext_vector_type(4)));
typedef float    f32x4 __attribute__((ext_vector_type(4)));

__device__ __forceinline__ unsigned f2key(float f) {
    union { float f; unsigned u; } cv; cv.f = f;
    unsigned u = cv.u;
    return u ^ ((unsigned)((int)u >> 31) | 0x80000000u);  // monotonic float->uint
}

__device__ __forceinline__ void ld16(const _Float16* g, _Float16* l) {
    __builtin_amdgcn_global_load_lds(
        (const __attribute__((address_space(1))) void*)g,
        (__attribute__((address_space(3))) void*)l, 16, 0, 0);
}

// ---------------- split conversions (interleaved layout) ----------------
// v*64 = hi + lo/4096. A2[m][c*64 + (k&31)] = hi, +32 = lo, c = k>>5.
__global__ __launch_bounds__(256) void conv_a_kernel(
    const float* __restrict__ A, _Float16* __restrict__ A2)
{
    const int gid = blockIdx.x * 256 + threadIdx.x;
    const int m = gid / (KDIM / 4);
    const int k = (gid % (KDIM / 4)) * 4;       // 4-aligned, stays in one 32-chunk
    const float4 v = *(const float4*)(A + (size_t)m * KDIM + k);
    const float vv[4] = { v.x, v.y, v.z, v.w };
    f16x4 h, l;
#pragma unroll
    for (int j = 0; j < 4; ++j) {
        const float sv = vv[j] * 64.f;
        const _Float16 hh = (_Float16)sv;
        h[j] = hh;
        l[j] = (_Float16)((sv - (float)hh) * 4096.f);
    }
    const size_t ob = (size_t)m * VKD + (k >> 5) * 64 + (k & 31);
    *(f16x4*)(A2 + ob)      = h;
    *(f16x4*)(A2 + ob + 32) = l;
}

// W_enc (K=3072, N=16384) row-major -> B2[n][vk] interleaved hi/lo.
// Writes: 16 consecutive lanes cover one 256B contiguous run of one n-row.
__global__ __launch_bounds__(256) void conv_bt_kernel(
    const float* __restrict__ B, _Float16* __restrict__ B2)
{
    __shared__ float ts[64][65];
    const int n0 = blockIdx.x * 64;
    const int k0 = blockIdx.y * 64;
    const int tid = threadIdx.x;
#pragma unroll
    for (int i = 0; i < 4; ++i) {
        const int r = (tid >> 4) + i * 16;
        const int c = (tid & 15) * 4;
        const float4 v = *(const float4*)(B + (size_t)(k0 + r) * NSAE + n0 + c);
        ts[r][c] = v.x; ts[r][c + 1] = v.y; ts[r][c + 2] = v.z; ts[r][c + 3] = v.w;
    }
    __syncthreads();
    // block spans 2 vk-chunks = 128 vk = 256 B per n-row; 16 parts x 16B.
    const int part = tid & 15;
    const int vk = part * 8;
    const int chunk = vk >> 6;                  // 0 or 1
    const int off = vk & 63;
    const bool lo = off >= 32;
    const int kb = chunk * 32 + (off & 31);     // local real-k base, 0..56
#pragma unroll
    for (int g = 0; g < 4; ++g) {
        const int nl = (tid >> 4) + g * 16;
        f16x8 o;
#pragma unroll
        for (int j = 0; j < 8; ++j) {
            const float sv = ts[kb + j][nl] * 64.f;
            const _Float16 hh = (_Float16)sv;
            o[j] = lo ? (_Float16)((sv - (float)hh) * 4096.f) : hh;
        }
        const size_t ob = (size_t)(n0 + nl) * VKD + (size_t)(k0 >> 5) * 64 + vk;
        *(f16x8*)(B2 + ob) = o;
    }
}

// ---------------- MFMA GEMM: pre = (A @ B) + bias, emulated f32 ----------------
// 128x128 tile, 4 waves (2x2), dbuf LDS [2][128][64] f16 per matrix (64KB).
// Per K-step: STAGE(next buf) -> vmcnt(8) -> barrier -> {ds_read frags +
// 48 MFMA, compiler-interleaved fine-grained lgkmcnt} -> barrier.
__global__ __launch_bounds__(256, 2) void gemm_f16split_kernel(
    const _Float16* __restrict__ A2, const _Float16* __restrict__ B2,
    const float* __restrict__ bias, float* __restrict__ pre)
{
    __shared__ _Float16 sA[2 * 128 * 64];
    __shared__ _Float16 sB[2 * 128 * 64];
    const int tid = threadIdx.x;
    const int lane = tid & 63;
    const int wid = tid >> 6;
    const int wm = wid >> 1;
    const int wn = wid & 1;

    // T1: chunked XCD swizzle (bijective: 1024 % 8 == 0).
    const int bid = blockIdx.x;
    const int swz = (bid & 7) * 128 + (bid >> 3);
    const int m0 = (swz & 7) * 128;
    const int n0 = (swz >> 3) * 128;

    // staging: LDS dest linear, global source carries inverse swizzle (G21).
    const _Float16* pa[4]; const _Float16* pb[4];
    _Float16* da[4]; _Float16* db[4];
#pragma unroll
    for (int r = 0; r < 4; ++r) {
        const int d = tid + r * 256;
        const int row = d >> 3;
        const int ls = (d & 7) ^ (row & 7);
        pa[r] = A2 + (size_t)(m0 + row) * VKD + ls * 8;
        pb[r] = B2 + (size_t)(n0 + row) * VKD + ls * 8;
        da[r] = sA + d * 8;
        db[r] = sB + d * 8;
    }

    // fragment read offsets (swizzled): slot' = (4h+qw) ^ (rl&7)
    const int rl = lane & 15;
    const int qw = lane >> 4;
    const int aoff0 = ((0 + qw) ^ (rl & 7)) * 8 + rl * 64;   // hi half
    const int aoff1 = ((4 + qw) ^ (rl & 7)) * 8 + rl * 64;   // lo half

    f32x4 acc1[4][4], acc2[4][4];
#pragma unroll
    for (int mi = 0; mi < 4; ++mi)
#pragma unroll
        for (int ni = 0; ni < 4; ++ni) {
            acc1[mi][ni] = (f32x4){0.f, 0.f, 0.f, 0.f};
            acc2[mi][ni] = (f32x4){0.f, 0.f, 0.f, 0.f};
        }

    // prologue: stage tile 0 into buf 0
#pragma unroll
    for (int r = 0; r < 4; ++r) { ld16(pa[r], da[r]); ld16(pb[r], db[r]); }

    for (int kt = 0; kt < KT96; ++kt) {
        const int cb = (kt & 1) ? 8192 : 0;
        const int nb = cb ^ 8192;
        if (kt + 1 < KT96) {
            const int ko = (kt + 1) * 64;
#pragma unroll
            for (int r = 0; r < 4; ++r) {
                ld16(pa[r] + ko, da[r] + nb);
                ld16(pb[r] + ko, db[r] + nb);
            }
            asm volatile("s_waitcnt vmcnt(8)" ::: "memory");  // cur tile landed
        } else {
            asm volatile("s_waitcnt vmcnt(0)" ::: "memory");
        }
        __builtin_amdgcn_sched_barrier(0);
        __builtin_amdgcn_s_barrier();            // stage-for-cur visible everywhere
        __builtin_amdgcn_sched_barrier(0);

        __builtin_amdgcn_s_setprio(1);
        f16x8 af[4][2], bf[4][2];
#pragma unroll
        for (int i = 0; i < 4; ++i) {
            const int ra = cb + (wm * 64 + i * 16) * 64;
            const int rb = cb + (wn * 64 + i * 16) * 64;
            af[i][0] = *(const f16x8*)(sA + ra + aoff0);
            af[i][1] = *(const f16x8*)(sA + ra + aoff1);
            bf[i][0] = *(const f16x8*)(sB + rb + aoff0);
            bf[i][1] = *(const f16x8*)(sB + rb + aoff1);
        }
        // no explicit lgkm drain: compiler emits fine-grained lgkmcnt so
        // early MFMAs overlap later ds_reads.
#pragma unroll
        for (int mi = 0; mi < 4; ++mi)
#pragma unroll
            for (int ni = 0; ni < 4; ++ni) {
                acc1[mi][ni] = __builtin_amdgcn_mfma_f32_16x16x32_f16(af[mi][0], bf[ni][0], acc1[mi][ni], 0, 0, 0);
                acc2[mi][ni] = __builtin_amdgcn_mfma_f32_16x16x32_f16(af[mi][0], bf[ni][1], acc2[mi][ni], 0, 0, 0);
                acc2[mi][ni] = __builtin_amdgcn_mfma_f32_16x16x32_f16(af[mi][1], bf[ni][0], acc2[mi][ni], 0, 0, 0);
            }
        __builtin_amdgcn_s_setprio(0);
        __builtin_amdgcn_sched_barrier(0);       // pin reads+MFMAs above barrier
        __builtin_amdgcn_s_barrier();            // all waves done reading cur buf
    }

    // epilogue: pre = acc1*2^-12 + acc2*2^-24 + bias
    const float c12 = 1.0f / 4096.0f;
    const float c24 = 1.0f / 16777216.0f;
    float bv[4];
#pragma unroll
    for (int ni = 0; ni < 4; ++ni) bv[ni] = bias[n0 + wn * 64 + ni * 16 + rl];
#pragma unroll
    for (int mi = 0; mi < 4; ++mi)
#pragma unroll
        for (int ni = 0; ni < 4; ++ni)
#pragma unroll
            for (int r = 0; r < 4; ++r) {
                const int row = m0 + wm * 64 + mi * 16 + qw * 4 + r;
                const int col = n0 + wn * 64 + ni * 16 + rl;
                pre[(size_t)row * NSAE + col] =
                    acc1[mi][ni][r] * c12 + acc2[mi][ni][r] * c24 + bv[ni];
            }
}

// ---------------- f32 fallback GEMM (R1, known-good) ----------------
__global__ __launch_bounds__(256) void gemm_pre_kernel(
    const float* __restrict__ A, const float* __restrict__ Bm,
    const float* __restrict__ bias, float* __restrict__ pre)
{
    __shared__ float As[16][128];
    __shared__ float Bs[16][128];
    const int bn = blockIdx.x * 128;
    const int bm = blockIdx.y * 128;
    const int tid = threadIdx.x;
    const int tx = tid & 15;
    const int ty = tid >> 4;

    float acc[8][8];
#pragma unroll
    for (int i = 0; i < 8; ++i)
#pragma unroll
        for (int j = 0; j < 8; ++j) acc[i][j] = 0.f;

    for (int k0 = 0; k0 < KDIM; k0 += 16) {
#pragma unroll
        for (int i = 0; i < 2; ++i) {
            const int idx = i * 256 + tid;
            const int r = idx >> 2;
            const int c = (idx & 3) << 2;
            const float4 v = *(const float4*)(A + (size_t)(bm + r) * KDIM + (k0 + c));
            As[c + 0][r] = v.x; As[c + 1][r] = v.y;
            As[c + 2][r] = v.z; As[c + 3][r] = v.w;
        }
#pragma unroll
        for (int i = 0; i < 2; ++i) {
            const int idx = i * 256 + tid;
            const int r = idx >> 5;
            const int c = (idx & 31) << 2;
            *(float4*)(&Bs[r][c]) = *(const float4*)(Bm + (size_t)(k0 + r) * NSAE + (bn + c));
        }
        __syncthreads();
#pragma unroll
        for (int kk = 0; kk < 16; ++kk) {
            const float4 a0 = *(const float4*)(&As[kk][ty * 8]);
            const float4 a1 = *(const float4*)(&As[kk][ty * 8 + 4]);
            const float4 b0 = *(const float4*)(&Bs[kk][tx * 8]);
            const float4 b1 = *(const float4*)(&Bs[kk][tx * 8 + 4]);
            const float av[8] = { a0.x, a0.y, a0.z, a0.w, a1.x, a1.y, a1.z, a1.w };
            const float bv[8] = { b0.x, b0.y, b0.z, b0.w, b1.x, b1.y, b1.z, b1.w };
#pragma unroll
            for (int i = 0; i < 8; ++i)
#pragma unroll
                for (int j = 0; j < 8; ++j)
                    acc[i][j] = fmaf(av[i], bv[j], acc[i][j]);
        }
        __syncthreads();
    }

    float bv8[8];
#pragma unroll
    for (int j = 0; j < 8; ++j) bv8[j] = bias[bn + tx * 8 + j];
#pragma unroll
    for (int i = 0; i < 8; ++i) {
        float4 o0, o1;
        o0.x = acc[i][0] + bv8[0]; o0.y = acc[i][1] + bv8[1];
        o0.z = acc[i][2] + bv8[2]; o0.w = acc[i][3] + bv8[3];
        o1.x = acc[i][4] + bv8[4]; o1.y = acc[i][5] + bv8[5];
        o1.z = acc[i][6] + bv8[6]; o1.w = acc[i][7] + bv8[7];
        const size_t off = (size_t)(bm + ty * 8 + i) * NSAE + bn + tx * 8;
        *(float4*)(pre + off) = o0;
        *(float4*)(pre + off + 4) = o1;
    }
}

// ---------------- per-row radix top-64, row held in registers ----------------
// one block per row; 64 f32/thread in registers (static indices); per-wave
// private hists cut atomic contention 4x; zero global re-reads of the row.
__global__ __launch_bounds__(256) void topk_kernel(
    const float* __restrict__ pre,
    int* __restrict__ tk_idx, float* __restrict__ tk_val,
    float* __restrict__ z)
{
    __shared__ unsigned hist[4][256];
    __shared__ int sel[NK];
    __shared__ float sval[NK];
    __shared__ int ties[256];
    __shared__ float tval[256];
    __shared__ unsigned sh_prefix, sh_want, sh_cnt, sh_tiecnt;

    const int b = blockIdx.x;
    const int tid = threadIdx.x;
    const int w = tid >> 6;
    const float* row = pre + (size_t)b * NSAE;
    float* zrow = z + (size_t)b * NSAE;

    if (tid == 0) { sh_prefix = 0u; sh_want = NK; sh_cnt = 0u; sh_tiecnt = 0u; }
    hist[0][tid] = 0u; hist[1][tid] = 0u; hist[2][tid] = 0u; hist[3][tid] = 0u;
    __syncthreads();

    // load row (registers) + zero z + MSB-8 histogram (pass 0)
    float4 rv[16];
#pragma unroll
    for (int j = 0; j < 16; ++j) {
        const int i = tid * 4 + j * 1024;
        rv[j] = *(const float4*)(row + i);
        *(float4*)(zrow + i) = make_float4(0.f, 0.f, 0.f, 0.f);
        atomicAdd(&hist[w][f2key(rv[j].x) >> 24], 1u);
        atomicAdd(&hist[w][f2key(rv[j].y) >> 24], 1u);
        atomicAdd(&hist[w][f2key(rv[j].z) >> 24], 1u);
        atomicAdd(&hist[w][f2key(rv[j].w) >> 24], 1u);
    }
    __syncthreads();
    hist[0][tid] += hist[1][tid] + hist[2][tid] + hist[3][tid];
    __syncthreads();
    if (tid == 0) {
        unsigned cum = 0u; int bsel = 0;
        for (int bin = 255; bin >= 0; --bin) {
            const unsigned c = hist[0][bin];
            if (cum + c >= NK) { bsel = bin; break; }
            cum += c;
        }
        sh_prefix = ((unsigned)bsel << 24);
        sh_want = NK - cum;
    }
    __syncthreads();

    for (int pass = 1; pass < 4; ++pass) {
        hist[0][tid] = 0u; hist[1][tid] = 0u; hist[2][tid] = 0u; hist[3][tid] = 0u;
        __syncthreads();
        const int shift = 24 - pass * 8;
        const unsigned mask = 0xFFFFFFFFu << (shift + 8);
        const unsigned pfx = sh_prefix;
#pragma unroll
        for (int j = 0; j < 16; ++j) {
            const float fv[4] = { rv[j].x, rv[j].y, rv[j].z, rv[j].w };
#pragma unroll
            for (int q = 0; q < 4; ++q) {
                const unsigned k = f2key(fv[q]);
                if ((k & mask) == pfx) atomicAdd(&hist[w][(k >> shift) & 0xFFu], 1u);
            }
        }
        __syncthreads();
        hist[0][tid] += hist[1][tid] + hist[2][tid] + hist[3][tid];
        __syncthreads();
        if (tid == 0) {
            const unsigned want = sh_want;
            unsigned cum = 0u; int bsel = 0;
            for (int bin = 255; bin >= 0; --bin) {
                const unsigned c = hist[0][bin];
                if (cum + c >= want) { bsel = bin; break; }
                cum += c;
            }
            sh_prefix |= ((unsigned)bsel << shift);
            sh_want = want - cum;
        }
        __syncthreads();
    }

    const unsigned T = sh_prefix;   // key of 64th-largest
#pragma unroll
    for (int j = 0; j < 16; ++j) {
        const float fv[4] = { rv[j].x, rv[j].y, rv[j].z, rv[j].w };
#pragma unroll
        for (int q = 0; q < 4; ++q) {
            const unsigned k = f2key(fv[q]);
            if (k > T) {
                const unsigned s = atomicAdd(&sh_cnt, 1u);
                sel[s] = tid * 4 + j * 1024 + q;
                sval[s] = fv[q];
            } else if (k == T) {
                const unsigned s = atomicAdd(&sh_tiecnt, 1u);
                if (s < 256u) { ties[s] = tid * 4 + j * 1024 + q; tval[s] = fv[q]; }
            }
        }
    }
    __syncthreads();
    if (tid == 0) {
        const unsigned tc = sh_tiecnt;
        const int n = (int)(tc < 256u ? tc : 256u);
        for (int a = 1; a < n; ++a) {           // sort ties by index (with value)
            const int v = ties[a]; const float fv = tval[a]; int c = a;
            while (c > 0 && ties[c - 1] > v) {
                ties[c] = ties[c - 1]; tval[c] = tval[c - 1]; --c;
            }
            ties[c] = v; tval[c] = fv;
        }
        const int base = (int)sh_cnt;
        const int want = (int)sh_want;
        for (int j = 0; j < want && j < n; ++j) {
            sel[base + j] = ties[j]; sval[base + j] = tval[j];
        }
    }
    __syncthreads();
    if (tid < NK) {
        const int myi = sel[tid];
        int rank = 0;                            // canonical (ascending-idx) order
#pragma unroll 1
        for (int j = 0; j < NK; ++j) rank += (sel[j] < myi) ? 1 : 0;
        const float v = fmaxf(sval[tid], 0.f);   // relu
        tk_idx[b * NK + rank] = myi;
        tk_val[b * NK + rank] = v;
        zrow[myi] = v;
    }
}

// ---------------- inverse permutation ----------------
__global__ __launch_bounds__(256) void invperm_kernel(
    const int* __restrict__ perm, int* __restrict__ ipos)
{
    const int i = blockIdx.x * 256 + threadIdx.x;
    if (i < NT * NSAE) {
        const int t = i >> 14;
        ipos[t * NSAE + perm[i]] = i & (NSAE - 1);
    }
}

// ---------------- sparse decode + SSE partials ----------------
__global__ __launch_bounds__(256) void decode_kernel(
    const float* __restrict__ x,
    const int* __restrict__ tk_idx, const float* __restrict__ tk_val,
    const int* __restrict__ ipos,
    const float* __restrict__ Wd0, const float* __restrict__ bd0,
    const float* __restrict__ Wd1, const float* __restrict__ bd1,
    float* __restrict__ xhat, float* __restrict__ part0, float* __restrict__ part1)
{
    const int bt = blockIdx.x;
    const int b = bt >> 2;
    const int t = bt & 3;
    const int tid = threadIdx.x;

    __shared__ int s_p[NK];
    __shared__ float s_v[NK];
    if (tid < NK) {
        const int s = tk_idx[b * NK + tid];
        s_v[tid] = tk_val[b * NK + tid];
        s_p[tid] = ipos[t * NSAE + s];
    }
    __syncthreads();

    float acc0[3], acc1[3];
#pragma unroll
    for (int r = 0; r < 3; ++r) {
        const int d = tid + 256 * r;
        acc0[r] = bd0[t * NDIN + d];
        acc1[r] = bd1[t * NDIN + d];
    }
    for (int j = 0; j < NK; ++j) {
        const int p = s_p[j];
        const float v = s_v[j];
        const float* w1 = Wd1 + ((size_t)p * NT + t) * NDIN;
#pragma unroll
        for (int r = 0; r < 3; ++r) acc1[r] = fmaf(v, w1[tid + 256 * r], acc1[r]);
        if (p < PFX0) {
            const float* w0 = Wd0 + ((size_t)p * NT + t) * NDIN;
#pragma unroll
            for (int r = 0; r < 3; ++r) acc0[r] = fmaf(v, w0[tid + 256 * r], acc0[r]);
        }
    }

    float e0 = 0.f, e1 = 0.f;
#pragma unroll
    for (int r = 0; r < 3; ++r) {
        const int d = tid + 256 * r;
        const float xv = x[(size_t)bt * NDIN + d];
        const float d0 = acc0[r] - xv;
        const float d1 = acc1[r] - xv;
        e0 = fmaf(d0, d0, e0);
        e1 = fmaf(d1, d1, e1);
        xhat[(size_t)bt * NDIN + d] = acc1[r];
    }

    __shared__ float r0[256];
    __shared__ float r1[256];
    r0[tid] = e0; r1[tid] = e1;
    __syncthreads();
    for (int w = 128; w > 0; w >>= 1) {
        if (tid < w) { r0[tid] += r0[tid + w]; r1[tid] += r1[tid + w]; }
        __syncthreads();
    }
    if (tid == 0) { part0[bt] = r0[0]; part1[bt] = r1[0]; }
}

// ---------------- final deterministic loss reduce ----------------
__global__ __launch_bounds__(256) void reduce_kernel(
    const float* __restrict__ part0, const float* __restrict__ part1,
    float* __restrict__ out_total)
{
    __shared__ double red[256];
    const int tid = threadIdx.x;
    double s = 0.0;
    for (int i = tid; i < NB * NT; i += 256)
        s += (double)part0[i] + (double)part1[i];
    red[tid] = s;
    __syncthreads();
    for (int w = 128; w > 0; w >>= 1) {
        if (tid < w) red[tid] += red[tid + w];
        __syncthreads();
    }
    if (tid == 0) out_total[0] = (float)(red[0] / ((double)NB * (double)(NT * 2)));
}

extern "C" void kernel_launch(void* const* d_in, const int* in_sizes, int n_in,
                              void* d_out, int out_size, void* d_ws, size_t ws_size,
                              hipStream_t stream)
{
    const float* x     = (const float*)d_in[0];
    const float* W_enc = (const float*)d_in[1];
    const float* b_enc = (const float*)d_in[2];
    const float* Wd0   = (const float*)d_in[3];
    const float* bd0   = (const float*)d_in[4];
    const float* Wd1   = (const float*)d_in[5];
    const float* bd1   = (const float*)d_in[6];
    const int*   perm  = (const int*)d_in[7];

    float* out       = (float*)d_out;
    float* out_total = out;
    float* out_xhat  = out + 1;
    float* out_z     = out + 1 + (size_t)NB * NT * NDIN;

    char* ws = (char*)d_ws;
    size_t off = 0;
    float* pre = (float*)(ws + off); off += (size_t)NB * NSAE * sizeof(float);

    const size_t szA2 = (size_t)NB * VKD * sizeof(_Float16);     // 12.6 MB
    const size_t szB2 = (size_t)NSAE * VKD * sizeof(_Float16);   // 201.3 MB
    _Float16* A2 = (_Float16*)(ws + off);
    _Float16* B2 = (_Float16*)(ws + off + szA2);
    const size_t off_splits_end = off + szA2 + szB2;

    const bool fast = (ws_size >= off_splits_end +
        ((size_t)NB * NK * 8 + (size_t)NT * NSAE * 4 + (size_t)NB * NT * 8));
    size_t tail = fast ? off_splits_end : off;
    int*   tk_idx = (int*)(ws + tail);   tail += (size_t)NB * NK * sizeof(int);
    float* tk_val = (float*)(ws + tail); tail += (size_t)NB * NK * sizeof(float);
    int*   ipos   = (int*)(ws + tail);   tail += (size_t)NT * NSAE * sizeof(int);
    float* part0  = (float*)(ws + tail); tail += (size_t)NB * NT * sizeof(float);
    float* part1  = (float*)(ws + tail);

    if (fast) {
        conv_a_kernel<<<(NB * KDIM) / (256 * 4), 256, 0, stream>>>(x, A2);
        conv_bt_kernel<<<dim3(NSAE / 64, KDIM / 64), 256, 0, stream>>>(W_enc, B2);
        gemm_f16split_kernel<<<1024, 256, 0, stream>>>(A2, B2, b_enc, pre);
    } else {
        gemm_pre_kernel<<<dim3(NSAE / 128, NB / 128), 256, 0, stream>>>(x, W_enc, b_enc, pre);
    }
    invperm_kernel<<<(NT * NSAE) / 256, 256, 0, stream>>>(perm, ipos);
    topk_kernel<<<NB, 256, 0, stream>>>(pre, tk_idx, tk_val, out_z);
    decode_kernel<<<NB * NT, 256, 0, stream>>>(x, tk_idx, tk_val, ipos,
                                               Wd0, bd0, Wd1, bd1,
                                               out_xhat, part0, part1);
    reduce_kernel<<<1, 256, 0, stream>>>(part0, part1, out_total);
}

// Round 7
// 637.300 us; speedup vs baseline: 2.3709x; 1.0068x over previous
//
// R5: (1) single-accumulator emulated-f32 GEMM: lo limbs stored UNBOOSTED
//     (same scale domain as hi products) -> one f32 acc, 3 chained MFMAs,
//     halves acc VGPRs (prep for 256sq/8-phase port next round).
// (2) decode t-major grid: per-t gather working set ~75MB fits LLC.
// All other kernels identical to R4 (passed, absmax 0.03125).
#include <hip/hip_runtime.h>
#include <hip/hip_bf16.h>
#include <stdint.h>

#define NB    1024
#define NT    4
#define NDIN  768
#define NSAE  16384
#define NK    64
#define KDIM  3072
#define PFX0  8192
#define KT96  96          // K-steps of 32 real K (64 virtual)
#define VKD   6144        // virtual K per row (2*KDIM)

typedef _Float16 f16x8 __attribute__((ext_vector_type(8)));
typedef _Float16 f16x4 __attribute__((ext_vector_type(4)));
typedef float    f32x4 __attribute__((ext_vector_type(4)));

__device__ __forceinline__ unsigned f2key(float f) {
    union { float f; unsigned u; } cv; cv.f = f;
    unsigned u = cv.u;
    return u ^ ((unsigned)((int)u >> 31) | 0x80000000u);  // monotonic float->uint
}

__device__ __forceinline__ void ld16(const _Float16* g, _Float16* l) {
    __builtin_amdgcn_global_load_lds(
        (const __attribute__((address_space(1))) void*)g,
        (__attribute__((address_space(3))) void*)l, 16, 0, 0);
}

// ---------------- split conversions (interleaved layout) ----------------
// sv = v*64; hi = fp16(sv); lo = fp16(sv - hi)  [UNBOOSTED: same scale as hi]
// a*64 = hi + lo exactly (to fp16 rounding of lo); single-acc GEMM then
// computes (ah*bh + ah*bl + al*bh) all at the 4096x scale.
__global__ __launch_bounds__(256) void conv_a_kernel(
    const float* __restrict__ A, _Float16* __restrict__ A2)
{
    const int gid = blockIdx.x * 256 + threadIdx.x;
    const int m = gid / (KDIM / 4);
    const int k = (gid % (KDIM / 4)) * 4;       // 4-aligned, stays in one 32-chunk
    const float4 v = *(const float4*)(A + (size_t)m * KDIM + k);
    const float vv[4] = { v.x, v.y, v.z, v.w };
    f16x4 h, l;
#pragma unroll
    for (int j = 0; j < 4; ++j) {
        const float sv = vv[j] * 64.f;
        const _Float16 hh = (_Float16)sv;
        h[j] = hh;
        l[j] = (_Float16)(sv - (float)hh);      // unboosted
    }
    const size_t ob = (size_t)m * VKD + (k >> 5) * 64 + (k & 31);
    *(f16x4*)(A2 + ob)      = h;
    *(f16x4*)(A2 + ob + 32) = l;
}

// W_enc (K=3072, N=16384) row-major -> B2[n][vk] interleaved hi/lo.
// Writes: 16 consecutive lanes cover one 256B contiguous run of one n-row.
__global__ __launch_bounds__(256) void conv_bt_kernel(
    const float* __restrict__ B, _Float16* __restrict__ B2)
{
    __shared__ float ts[64][65];
    const int n0 = blockIdx.x * 64;
    const int k0 = blockIdx.y * 64;
    const int tid = threadIdx.x;
#pragma unroll
    for (int i = 0; i < 4; ++i) {
        const int r = (tid >> 4) + i * 16;
        const int c = (tid & 15) * 4;
        const float4 v = *(const float4*)(B + (size_t)(k0 + r) * NSAE + n0 + c);
        ts[r][c] = v.x; ts[r][c + 1] = v.y; ts[r][c + 2] = v.z; ts[r][c + 3] = v.w;
    }
    __syncthreads();
    // block spans 2 vk-chunks = 128 vk = 256 B per n-row; 16 parts x 16B.
    const int part = tid & 15;
    const int vk = part * 8;
    const int chunk = vk >> 6;                  // 0 or 1
    const int off = vk & 63;
    const bool lo = off >= 32;
    const int kb = chunk * 32 + (off & 31);     // local real-k base, 0..56
#pragma unroll
    for (int g = 0; g < 4; ++g) {
        const int nl = (tid >> 4) + g * 16;
        f16x8 o;
#pragma unroll
        for (int j = 0; j < 8; ++j) {
            const float sv = ts[kb + j][nl] * 64.f;
            const _Float16 hh = (_Float16)sv;
            o[j] = lo ? (_Float16)(sv - (float)hh) : hh;   // unboosted lo
        }
        const size_t ob = (size_t)(n0 + nl) * VKD + (size_t)(k0 >> 5) * 64 + vk;
        *(f16x8*)(B2 + ob) = o;
    }
}

// ---------------- MFMA GEMM: pre = (A @ B) + bias, emulated f32 ----------------
// 128x128 tile, 4 waves (2x2), dbuf LDS [2][128][64] f16 per matrix (64KB).
// SINGLE f32 accumulator: all three limb products share the 4096x scale.
// Per K-step: STAGE(next buf) -> vmcnt(8) -> barrier -> ds_read + 48 MFMA
// (compiler-interleaved) -> barrier. XOR-8 slot swizzle (G21 both-sides).
__global__ __launch_bounds__(256, 2) void gemm_f16split_kernel(
    const _Float16* __restrict__ A2, const _Float16* __restrict__ B2,
    const float* __restrict__ bias, float* __restrict__ pre)
{
    __shared__ _Float16 sA[2 * 128 * 64];
    __shared__ _Float16 sB[2 * 128 * 64];
    const int tid = threadIdx.x;
    const int lane = tid & 63;
    const int wid = tid >> 6;
    const int wm = wid >> 1;
    const int wn = wid & 1;

    // T1: chunked XCD swizzle (bijective: 1024 % 8 == 0).
    const int bid = blockIdx.x;
    const int swz = (bid & 7) * 128 + (bid >> 3);
    const int m0 = (swz & 7) * 128;
    const int n0 = (swz >> 3) * 128;

    // staging: LDS dest linear, global source carries inverse swizzle (G21).
    const _Float16* pa[4]; const _Float16* pb[4];
    _Float16* da[4]; _Float16* db[4];
#pragma unroll
    for (int r = 0; r < 4; ++r) {
        const int d = tid + r * 256;
        const int row = d >> 3;
        const int ls = (d & 7) ^ (row & 7);
        pa[r] = A2 + (size_t)(m0 + row) * VKD + ls * 8;
        pb[r] = B2 + (size_t)(n0 + row) * VKD + ls * 8;
        da[r] = sA + d * 8;
        db[r] = sB + d * 8;
    }

    // fragment read offsets (swizzled): slot' = (4h+qw) ^ (rl&7)
    const int rl = lane & 15;
    const int qw = lane >> 4;
    const int aoff0 = ((0 + qw) ^ (rl & 7)) * 8 + rl * 64;   // hi half
    const int aoff1 = ((4 + qw) ^ (rl & 7)) * 8 + rl * 64;   // lo half

    f32x4 acc[4][4];
#pragma unroll
    for (int mi = 0; mi < 4; ++mi)
#pragma unroll
        for (int ni = 0; ni < 4; ++ni)
            acc[mi][ni] = (f32x4){0.f, 0.f, 0.f, 0.f};

    // prologue: stage tile 0 into buf 0
#pragma unroll
    for (int r = 0; r < 4; ++r) { ld16(pa[r], da[r]); ld16(pb[r], db[r]); }

    for (int kt = 0; kt < KT96; ++kt) {
        const int cb = (kt & 1) ? 8192 : 0;
        const int nb = cb ^ 8192;
        if (kt + 1 < KT96) {
            const int ko = (kt + 1) * 64;
#pragma unroll
            for (int r = 0; r < 4; ++r) {
                ld16(pa[r] + ko, da[r] + nb);
                ld16(pb[r] + ko, db[r] + nb);
            }
            asm volatile("s_waitcnt vmcnt(8)" ::: "memory");  // cur tile landed
        } else {
            asm volatile("s_waitcnt vmcnt(0)" ::: "memory");
        }
        __builtin_amdgcn_sched_barrier(0);
        __builtin_amdgcn_s_barrier();            // stage-for-cur visible everywhere
        __builtin_amdgcn_sched_barrier(0);

        __builtin_amdgcn_s_setprio(1);
        f16x8 af[4][2], bf[4][2];
#pragma unroll
        for (int i = 0; i < 4; ++i) {
            const int ra = cb + (wm * 64 + i * 16) * 64;
            const int rb = cb + (wn * 64 + i * 16) * 64;
            af[i][0] = *(const f16x8*)(sA + ra + aoff0);
            af[i][1] = *(const f16x8*)(sA + ra + aoff1);
            bf[i][0] = *(const f16x8*)(sB + rb + aoff0);
            bf[i][1] = *(const f16x8*)(sB + rb + aoff1);
        }
        // 16 independent (mi,ni) chains of 3 chained MFMAs -> ample ILP.
#pragma unroll
        for (int mi = 0; mi < 4; ++mi)
#pragma unroll
            for (int ni = 0; ni < 4; ++ni) {
                acc[mi][ni] = __builtin_amdgcn_mfma_f32_16x16x32_f16(af[mi][0], bf[ni][0], acc[mi][ni], 0, 0, 0);
                acc[mi][ni] = __builtin_amdgcn_mfma_f32_16x16x32_f16(af[mi][0], bf[ni][1], acc[mi][ni], 0, 0, 0);
                acc[mi][ni] = __builtin_amdgcn_mfma_f32_16x16x32_f16(af[mi][1], bf[ni][0], acc[mi][ni], 0, 0, 0);
            }
        __builtin_amdgcn_s_setprio(0);
        __builtin_amdgcn_sched_barrier(0);       // pin reads+MFMAs above barrier
        __builtin_amdgcn_s_barrier();            // all waves done reading cur buf
    }

    // epilogue: pre = acc*2^-12 + bias  (single scale: /(64*64))
    const float c12 = 1.0f / 4096.0f;
    float bv[4];
#pragma unroll
    for (int ni = 0; ni < 4; ++ni) bv[ni] = bias[n0 + wn * 64 + ni * 16 + rl];
#pragma unroll
    for (int mi = 0; mi < 4; ++mi)
#pragma unroll
        for (int ni = 0; ni < 4; ++ni)
#pragma unroll
            for (int r = 0; r < 4; ++r) {
                const int row = m0 + wm * 64 + mi * 16 + qw * 4 + r;
                const int col = n0 + wn * 64 + ni * 16 + rl;
                pre[(size_t)row * NSAE + col] = acc[mi][ni][r] * c12 + bv[ni];
            }
}

// ---------------- f32 fallback GEMM (R1, known-good) ----------------
__global__ __launch_bounds__(256) void gemm_pre_kernel(
    const float* __restrict__ A, const float* __restrict__ Bm,
    const float* __restrict__ bias, float* __restrict__ pre)
{
    __shared__ float As[16][128];
    __shared__ float Bs[16][128];
    const int bn = blockIdx.x * 128;
    const int bm = blockIdx.y * 128;
    const int tid = threadIdx.x;
    const int tx = tid & 15;
    const int ty = tid >> 4;

    float acc[8][8];
#pragma unroll
    for (int i = 0; i < 8; ++i)
#pragma unroll
        for (int j = 0; j < 8; ++j) acc[i][j] = 0.f;

    for (int k0 = 0; k0 < KDIM; k0 += 16) {
#pragma unroll
        for (int i = 0; i < 2; ++i) {
            const int idx = i * 256 + tid;
            const int r = idx >> 2;
            const int c = (idx & 3) << 2;
            const float4 v = *(const float4*)(A + (size_t)(bm + r) * KDIM + (k0 + c));
            As[c + 0][r] = v.x; As[c + 1][r] = v.y;
            As[c + 2][r] = v.z; As[c + 3][r] = v.w;
        }
#pragma unroll
        for (int i = 0; i < 2; ++i) {
            const int idx = i * 256 + tid;
            const int r = idx >> 5;
            const int c = (idx & 31) << 2;
            *(float4*)(&Bs[r][c]) = *(const float4*)(Bm + (size_t)(k0 + r) * NSAE + (bn + c));
        }
        __syncthreads();
#pragma unroll
        for (int kk = 0; kk < 16; ++kk) {
            const float4 a0 = *(const float4*)(&As[kk][ty * 8]);
            const float4 a1 = *(const float4*)(&As[kk][ty * 8 + 4]);
            const float4 b0 = *(const float4*)(&Bs[kk][tx * 8]);
            const float4 b1 = *(const float4*)(&Bs[kk][tx * 8 + 4]);
            const float av[8] = { a0.x, a0.y, a0.z, a0.w, a1.x, a1.y, a1.z, a1.w };
            const float bv[8] = { b0.x, b0.y, b0.z, b0.w, b1.x, b1.y, b1.z, b1.w };
#pragma unroll
            for (int i = 0; i < 8; ++i)
#pragma unroll
                for (int j = 0; j < 8; ++j)
                    acc[i][j] = fmaf(av[i], bv[j], acc[i][j]);
        }
        __syncthreads();
    }

    float bv8[8];
#pragma unroll
    for (int j = 0; j < 8; ++j) bv8[j] = bias[bn + tx * 8 + j];
#pragma unroll
    for (int i = 0; i < 8; ++i) {
        float4 o0, o1;
        o0.x = acc[i][0] + bv8[0]; o0.y = acc[i][1] + bv8[1];
        o0.z = acc[i][2] + bv8[2]; o0.w = acc[i][3] + bv8[3];
        o1.x = acc[i][4] + bv8[4]; o1.y = acc[i][5] + bv8[5];
        o1.z = acc[i][6] + bv8[6]; o1.w = acc[i][7] + bv8[7];
        const size_t off = (size_t)(bm + ty * 8 + i) * NSAE + bn + tx * 8;
        *(float4*)(pre + off) = o0;
        *(float4*)(pre + off + 4) = o1;
    }
}

// ---------------- per-row radix top-64, row held in registers ----------------
__global__ __launch_bounds__(256) void topk_kernel(
    const float* __restrict__ pre,
    int* __restrict__ tk_idx, float* __restrict__ tk_val,
    float* __restrict__ z)
{
    __shared__ unsigned hist[4][256];
    __shared__ int sel[NK];
    __shared__ float sval[NK];
    __shared__ int ties[256];
    __shared__ float tval[256];
    __shared__ unsigned sh_prefix, sh_want, sh_cnt, sh_tiecnt;

    const int b = blockIdx.x;
    const int tid = threadIdx.x;
    const int w = tid >> 6;
    const float* row = pre + (size_t)b * NSAE;
    float* zrow = z + (size_t)b * NSAE;

    if (tid == 0) { sh_prefix = 0u; sh_want = NK; sh_cnt = 0u; sh_tiecnt = 0u; }
    hist[0][tid] = 0u; hist[1][tid] = 0u; hist[2][tid] = 0u; hist[3][tid] = 0u;
    __syncthreads();

    // load row (registers) + zero z + MSB-8 histogram (pass 0)
    float4 rv[16];
#pragma unroll
    for (int j = 0; j < 16; ++j) {
        const int i = tid * 4 + j * 1024;
        rv[j] = *(const float4*)(row + i);
        *(float4*)(zrow + i) = make_float4(0.f, 0.f, 0.f, 0.f);
        atomicAdd(&hist[w][f2key(rv[j].x) >> 24], 1u);
        atomicAdd(&hist[w][f2key(rv[j].y) >> 24], 1u);
        atomicAdd(&hist[w][f2key(rv[j].z) >> 24], 1u);
        atomicAdd(&hist[w][f2key(rv[j].w) >> 24], 1u);
    }
    __syncthreads();
    hist[0][tid] += hist[1][tid] + hist[2][tid] + hist[3][tid];
    __syncthreads();
    if (tid == 0) {
        unsigned cum = 0u; int bsel = 0;
        for (int bin = 255; bin >= 0; --bin) {
            const unsigned c = hist[0][bin];
            if (cum + c >= NK) { bsel = bin; break; }
            cum += c;
        }
        sh_prefix = ((unsigned)bsel << 24);
        sh_want = NK - cum;
    }
    __syncthreads();

    for (int pass = 1; pass < 4; ++pass) {
        hist[0][tid] = 0u; hist[1][tid] = 0u; hist[2][tid] = 0u; hist[3][tid] = 0u;
        __syncthreads();
        const int shift = 24 - pass * 8;
        const unsigned mask = 0xFFFFFFFFu << (shift + 8);
        const unsigned pfx = sh_prefix;
#pragma unroll
        for (int j = 0; j < 16; ++j) {
            const float fv[4] = { rv[j].x, rv[j].y, rv[j].z, rv[j].w };
#pragma unroll
            for (int q = 0; q < 4; ++q) {
                const unsigned k = f2key(fv[q]);
                if ((k & mask) == pfx) atomicAdd(&hist[w][(k >> shift) & 0xFFu], 1u);
            }
        }
        __syncthreads();
        hist[0][tid] += hist[1][tid] + hist[2][tid] + hist[3][tid];
        __syncthreads();
        if (tid == 0) {
            const unsigned want = sh_want;
            unsigned cum = 0u; int bsel = 0;
            for (int bin = 255; bin >= 0; --bin) {
                const unsigned c = hist[0][bin];
                if (cum + c >= want) { bsel = bin; break; }
                cum += c;
            }
            sh_prefix |= ((unsigned)bsel << shift);
            sh_want = want - cum;
        }
        __syncthreads();
    }

    const unsigned T = sh_prefix;   // key of 64th-largest
#pragma unroll
    for (int j = 0; j < 16; ++j) {
        const float fv[4] = { rv[j].x, rv[j].y, rv[j].z, rv[j].w };
#pragma unroll
        for (int q = 0; q < 4; ++q) {
            const unsigned k = f2key(fv[q]);
            if (k > T) {
                const unsigned s = atomicAdd(&sh_cnt, 1u);
                sel[s] = tid * 4 + j * 1024 + q;
                sval[s] = fv[q];
            } else if (k == T) {
                const unsigned s = atomicAdd(&sh_tiecnt, 1u);
                if (s < 256u) { ties[s] = tid * 4 + j * 1024 + q; tval[s] = fv[q]; }
            }
        }
    }
    __syncthreads();
    if (tid == 0) {
        const unsigned tc = sh_tiecnt;
        const int n = (int)(tc < 256u ? tc : 256u);
        for (int a = 1; a < n; ++a) {           // sort ties by index (with value)
            const int v = ties[a]; const float fv = tval[a]; int c = a;
            while (c > 0 && ties[c - 1] > v) {
                ties[c] = ties[c - 1]; tval[c] = tval[c - 1]; --c;
            }
            ties[c] = v; tval[c] = fv;
        }
        const int base = (int)sh_cnt;
        const int want = (int)sh_want;
        for (int j = 0; j < want && j < n; ++j) {
            sel[base + j] = ties[j]; sval[base + j] = tval[j];
        }
    }
    __syncthreads();
    if (tid < NK) {
        const int myi = sel[tid];
        int rank = 0;                            // canonical (ascending-idx) order
#pragma unroll 1
        for (int j = 0; j < NK; ++j) rank += (sel[j] < myi) ? 1 : 0;
        const float v = fmaxf(sval[tid], 0.f);   // relu
        tk_idx[b * NK + rank] = myi;
        tk_val[b * NK + rank] = v;
        zrow[myi] = v;
    }
}

// ---------------- inverse permutation ----------------
__global__ __launch_bounds__(256) void invperm_kernel(
    const int* __restrict__ perm, int* __restrict__ ipos)
{
    const int i = blockIdx.x * 256 + threadIdx.x;
    if (i < NT * NSAE) {
        const int t = i >> 14;
        ipos[t * NSAE + perm[i]] = i & (NSAE - 1);
    }
}

// ---------------- sparse decode + SSE partials ----------------
// t-major grid: all blocks of one t dispatch together -> per-t decoder
// slices (~75MB) fit LLC -> gather re-reads become LLC hits.
__global__ __launch_bounds__(256) void decode_kernel(
    const float* __restrict__ x,
    const int* __restrict__ tk_idx, const float* __restrict__ tk_val,
    const int* __restrict__ ipos,
    const float* __restrict__ Wd0, const float* __restrict__ bd0,
    const float* __restrict__ Wd1, const float* __restrict__ bd1,
    float* __restrict__ xhat, float* __restrict__ part0, float* __restrict__ part1)
{
    const int gbid = blockIdx.x;
    const int t = gbid >> 10;                   // t-major
    const int b = gbid & (NB - 1);
    const int bt = b * NT + t;
    const int tid = threadIdx.x;

    __shared__ int s_p[NK];
    __shared__ float s_v[NK];
    if (tid < NK) {
        const int s = tk_idx[b * NK + tid];
        s_v[tid] = tk_val[b * NK + tid];
        s_p[tid] = ipos[t * NSAE + s];
    }
    __syncthreads();

    float acc0[3], acc1[3];
#pragma unroll
    for (int r = 0; r < 3; ++r) {
        const int d = tid + 256 * r;
        acc0[r] = bd0[t * NDIN + d];
        acc1[r] = bd1[t * NDIN + d];
    }
    for (int j = 0; j < NK; ++j) {
        const int p = s_p[j];
        const float v = s_v[j];
        const float* w1 = Wd1 + ((size_t)p * NT + t) * NDIN;
#pragma unroll
        for (int r = 0; r < 3; ++r) acc1[r] = fmaf(v, w1[tid + 256 * r], acc1[r]);
        if (p < PFX0) {
            const float* w0 = Wd0 + ((size_t)p * NT + t) * NDIN;
#pragma unroll
            for (int r = 0; r < 3; ++r) acc0[r] = fmaf(v, w0[tid + 256 * r], acc0[r]);
        }
    }

    float e0 = 0.f, e1 = 0.f;
#pragma unroll
    for (int r = 0; r < 3; ++r) {
        const int d = tid + 256 * r;
        const float xv = x[(size_t)bt * NDIN + d];
        const float d0 = acc0[r] - xv;
        const float d1 = acc1[r] - xv;
        e0 = fmaf(d0, d0, e0);
        e1 = fmaf(d1, d1, e1);
        xhat[(size_t)bt * NDIN + d] = acc1[r];
    }

    __shared__ float r0[256];
    __shared__ float r1[256];
    r0[tid] = e0; r1[tid] = e1;
    __syncthreads();
    for (int w = 128; w > 0; w >>= 1) {
        if (tid < w) { r0[tid] += r0[tid + w]; r1[tid] += r1[tid + w]; }
        __syncthreads();
    }
    if (tid == 0) { part0[bt] = r0[0]; part1[bt] = r1[0]; }
}

// ---------------- final deterministic loss reduce ----------------
__global__ __launch_bounds__(256) void reduce_kernel(
    const float* __restrict__ part0, const float* __restrict__ part1,
    float* __restrict__ out_total)
{
    __shared__ double red[256];
    const int tid = threadIdx.x;
    double s = 0.0;
    for (int i = tid; i < NB * NT; i += 256)
        s += (double)part0[i] + (double)part1[i];
    red[tid] = s;
    __syncthreads();
    for (int w = 128; w > 0; w >>= 1) {
        if (tid < w) red[tid] += red[tid + w];
        __syncthreads();
    }
    if (tid == 0) out_total[0] = (float)(red[0] / ((double)NB * (double)(NT * 2)));
}

extern "C" void kernel_launch(void* const* d_in, const int* in_sizes, int n_in,
                              void* d_out, int out_size, void* d_ws, size_t ws_size,
                              hipStream_t stream)
{
    const float* x     = (const float*)d_in[0];
    const float* W_enc = (const float*)d_in[1];
    const float* b_enc = (const float*)d_in[2];
    const float* Wd0   = (const float*)d_in[3];
    const float* bd0   = (const float*)d_in[4];
    const float* Wd1   = (const float*)d_in[5];
    const float* bd1   = (const float*)d_in[6];
    const int*   perm  = (const int*)d_in[7];

    float* out       = (float*)d_out;
    float* out_total = out;
    float* out_xhat  = out + 1;
    float* out_z     = out + 1 + (size_t)NB * NT * NDIN;

    char* ws = (char*)d_ws;
    size_t off = 0;
    float* pre = (float*)(ws + off); off += (size_t)NB * NSAE * sizeof(float);

    const size_t szA2 = (size_t)NB * VKD * sizeof(_Float16);     // 12.6 MB
    const size_t szB2 = (size_t)NSAE * VKD * sizeof(_Float16);   // 201.3 MB
    _Float16* A2 = (_Float16*)(ws + off);
    _Float16* B2 = (_Float16*)(ws + off + szA2);
    const size_t off_splits_end = off + szA2 + szB2;

    const bool fast = (ws_size >= off_splits_end +
        ((size_t)NB * NK * 8 + (size_t)NT * NSAE * 4 + (size_t)NB * NT * 8));
    size_t tail = fast ? off_splits_end : off;
    int*   tk_idx = (int*)(ws + tail);   tail += (size_t)NB * NK * sizeof(int);
    float* tk_val = (float*)(ws + tail); tail += (size_t)NB * NK * sizeof(float);
    int*   ipos   = (int*)(ws + tail);   tail += (size_t)NT * NSAE * sizeof(int);
    float* part0  = (float*)(ws + tail); tail += (size_t)NB * NT * sizeof(float);
    float* part1  = (float*)(ws + tail);

    if (fast) {
        conv_a_kernel<<<(NB * KDIM) / (256 * 4), 256, 0, stream>>>(x, A2);
        conv_bt_kernel<<<dim3(NSAE / 64, KDIM / 64), 256, 0, stream>>>(W_enc, B2);
        gemm_f16split_kernel<<<1024, 256, 0, stream>>>(A2, B2, b_enc, pre);
    } else {
        gemm_pre_kernel<<<dim3(NSAE / 128, NB / 128), 256, 0, stream>>>(x, W_enc, b_enc, pre);
    }
    invperm_kernel<<<(NT * NSAE) / 256, 256, 0, stream>>>(perm, ipos);
    topk_kernel<<<NB, 256, 0, stream>>>(pre, tk_idx, tk_val, out_z);
    decode_kernel<<<NB * NT, 256, 0, stream>>>(x, tk_idx, tk_val, ipos,
                                               Wd0, bd0, Wd1, bd1,
                                               out_xhat, part0, part1);
    reduce_kernel<<<1, 256, 0, stream>>>(part0, part1, out_total);
}

// Round 8
// 613.106 us; speedup vs baseline: 2.4645x; 1.0395x over previous
//
// R6: GEMM scaled to 256x256 tile, 8 waves (2Mx4N), 128KB dbuf LDS.
// Same proven 2-barrier K-step skeleton, XOR-8 swizzle, vmcnt(8), setprio,
// T1 chunked XCD swizzle. Single f32 acc (R5 numerics, validated).
// Per-wave: 128x64 out = acc[8][4]x4; operands streamed per m-half to cap VGPR.
// Downstream kernels identical to R5 (passed, absmax 0.03125).
#include <hip/hip_runtime.h>
#include <hip/hip_bf16.h>
#include <stdint.h>

#define NB    1024
#define NT    4
#define NDIN  768
#define NSAE  16384
#define NK    64
#define KDIM  3072
#define PFX0  8192
#define KT96  96          // K-steps of 32 real K (64 virtual)
#define VKD   6144        // virtual K per row (2*KDIM)

typedef _Float16 f16x8 __attribute__((ext_vector_type(8)));
typedef _Float16 f16x4 __attribute__((ext_vector_type(4)));
typedef float    f32x4 __attribute__((ext_vector_type(4)));

__device__ __forceinline__ unsigned f2key(float f) {
    union { float f; unsigned u; } cv; cv.f = f;
    unsigned u = cv.u;
    return u ^ ((unsigned)((int)u >> 31) | 0x80000000u);  // monotonic float->uint
}

__device__ __forceinline__ void ld16(const _Float16* g, _Float16* l) {
    __builtin_amdgcn_global_load_lds(
        (const __attribute__((address_space(1))) void*)g,
        (__attribute__((address_space(3))) void*)l, 16, 0, 0);
}

// ---------------- split conversions (interleaved layout) ----------------
// sv = v*64; hi = fp16(sv); lo = fp16(sv - hi)  [unboosted, same scale].
__global__ __launch_bounds__(256) void conv_a_kernel(
    const float* __restrict__ A, _Float16* __restrict__ A2)
{
    const int gid = blockIdx.x * 256 + threadIdx.x;
    const int m = gid / (KDIM / 4);
    const int k = (gid % (KDIM / 4)) * 4;       // 4-aligned, stays in one 32-chunk
    const float4 v = *(const float4*)(A + (size_t)m * KDIM + k);
    const float vv[4] = { v.x, v.y, v.z, v.w };
    f16x4 h, l;
#pragma unroll
    for (int j = 0; j < 4; ++j) {
        const float sv = vv[j] * 64.f;
        const _Float16 hh = (_Float16)sv;
        h[j] = hh;
        l[j] = (_Float16)(sv - (float)hh);      // unboosted
    }
    const size_t ob = (size_t)m * VKD + (k >> 5) * 64 + (k & 31);
    *(f16x4*)(A2 + ob)      = h;
    *(f16x4*)(A2 + ob + 32) = l;
}

// W_enc (K=3072, N=16384) row-major -> B2[n][vk] interleaved hi/lo.
__global__ __launch_bounds__(256) void conv_bt_kernel(
    const float* __restrict__ B, _Float16* __restrict__ B2)
{
    __shared__ float ts[64][65];
    const int n0 = blockIdx.x * 64;
    const int k0 = blockIdx.y * 64;
    const int tid = threadIdx.x;
#pragma unroll
    for (int i = 0; i < 4; ++i) {
        const int r = (tid >> 4) + i * 16;
        const int c = (tid & 15) * 4;
        const float4 v = *(const float4*)(B + (size_t)(k0 + r) * NSAE + n0 + c);
        ts[r][c] = v.x; ts[r][c + 1] = v.y; ts[r][c + 2] = v.z; ts[r][c + 3] = v.w;
    }
    __syncthreads();
    const int part = tid & 15;
    const int vk = part * 8;
    const int chunk = vk >> 6;                  // 0 or 1
    const int off = vk & 63;
    const bool lo = off >= 32;
    const int kb = chunk * 32 + (off & 31);     // local real-k base, 0..56
#pragma unroll
    for (int g = 0; g < 4; ++g) {
        const int nl = (tid >> 4) + g * 16;
        f16x8 o;
#pragma unroll
        for (int j = 0; j < 8; ++j) {
            const float sv = ts[kb + j][nl] * 64.f;
            const _Float16 hh = (_Float16)sv;
            o[j] = lo ? (_Float16)(sv - (float)hh) : hh;   // unboosted lo
        }
        const size_t ob = (size_t)(n0 + nl) * VKD + (size_t)(k0 >> 5) * 64 + vk;
        *(f16x8*)(B2 + ob) = o;
    }
}

// ---------------- MFMA GEMM: pre = (A @ B) + bias, emulated f32 ----------------
// 256x256 tile, 8 waves (2Mx4N), dbuf LDS [2][256][64] f16 per matrix (128KB).
// Per K-step: STAGE(next buf, 8x ld16) -> vmcnt(8) -> barrier ->
// {bf + af(m-half) ds_reads, 48+48 MFMA, compiler-interleaved lgkmcnt} ->
// barrier. XOR-8 slot swizzle (G21 both-sides). Single f32 accumulator.
__global__ __launch_bounds__(512, 2) void gemm_f16split_kernel(
    const _Float16* __restrict__ A2, const _Float16* __restrict__ B2,
    const float* __restrict__ bias, float* __restrict__ pre)
{
    __shared__ _Float16 sA[2 * 256 * 64];   // 64KB
    __shared__ _Float16 sB[2 * 256 * 64];   // 64KB
    const int tid = threadIdx.x;
    const int lane = tid & 63;
    const int wid = tid >> 6;     // 0..7
    const int wm = wid >> 2;      // 0..1  (M half)
    const int wn = wid & 3;       // 0..3  (N quarter)

    // T1 chunked XCD swizzle: 256 blocks, 256%8==0 -> bijective.
    // XCD x gets swz in [32x,32x+32): 8 n-panels x all 4 m-panels -> B reuse.
    const int bid = blockIdx.x;
    const int swz = (bid & 7) * 32 + (bid >> 3);
    const int m0 = (swz & 3) * 256;
    const int n0 = (swz >> 2) * 256;

    // staging: 4 rounds x 512 thr x 16B per matrix; LDS dest linear,
    // global source carries inverse XOR-8 swizzle (G21).
    const _Float16* pa[4]; const _Float16* pb[4];
    _Float16* da[4]; _Float16* db[4];
#pragma unroll
    for (int r = 0; r < 4; ++r) {
        const int d = tid + r * 512;          // 0..2047
        const int row = d >> 3;               // 0..255
        const int ls = (d & 7) ^ (row & 7);
        pa[r] = A2 + (size_t)(m0 + row) * VKD + ls * 8;
        pb[r] = B2 + (size_t)(n0 + row) * VKD + ls * 8;
        da[r] = sA + d * 8;
        db[r] = sB + d * 8;
    }

    // fragment read offsets (swizzled): slot' = (limb*4+qw) ^ (rl&7);
    // frag-row bases are multiples of 16 so (row&7)==(rl&7).
    const int rl = lane & 15;
    const int qw = lane >> 4;
    const int aoff0 = ((0 + qw) ^ (rl & 7)) * 8 + rl * 64;   // hi limb
    const int aoff1 = ((4 + qw) ^ (rl & 7)) * 8 + rl * 64;   // lo limb

    f32x4 acc[8][4];
#pragma unroll
    for (int mi = 0; mi < 8; ++mi)
#pragma unroll
        for (int ni = 0; ni < 4; ++ni)
            acc[mi][ni] = (f32x4){0.f, 0.f, 0.f, 0.f};

    // prologue: stage tile 0 into buf 0
#pragma unroll
    for (int r = 0; r < 4; ++r) { ld16(pa[r], da[r]); ld16(pb[r], db[r]); }

    for (int kt = 0; kt < KT96; ++kt) {
        const int cb = (kt & 1) ? 16384 : 0;
        const int nb = cb ^ 16384;
        if (kt + 1 < KT96) {
            const int ko = (kt + 1) * 64;
#pragma unroll
            for (int r = 0; r < 4; ++r) {
                ld16(pa[r] + ko, da[r] + nb);
                ld16(pb[r] + ko, db[r] + nb);
            }
            asm volatile("s_waitcnt vmcnt(8)" ::: "memory");  // cur tile landed
        } else {
            asm volatile("s_waitcnt vmcnt(0)" ::: "memory");
        }
        __builtin_amdgcn_sched_barrier(0);
        __builtin_amdgcn_s_barrier();            // stage-for-cur visible everywhere
        __builtin_amdgcn_sched_barrier(0);

        __builtin_amdgcn_s_setprio(1);
        // B fragments (whole wave-N strip, both limbs): 8x ds_read_b128
        f16x8 bf[4][2];
#pragma unroll
        for (int ni = 0; ni < 4; ++ni) {
            const int rb = cb + (wn * 64 + ni * 16) * 64;
            bf[ni][0] = *(const f16x8*)(sB + rb + aoff0);
            bf[ni][1] = *(const f16x8*)(sB + rb + aoff1);
        }
        // A fragments streamed per m-half to cap live registers.
#pragma unroll
        for (int h = 0; h < 2; ++h) {
            f16x8 af[4][2];
#pragma unroll
            for (int i = 0; i < 4; ++i) {
                const int ra = cb + (wm * 128 + (h * 4 + i) * 16) * 64;
                af[i][0] = *(const f16x8*)(sA + ra + aoff0);
                af[i][1] = *(const f16x8*)(sA + ra + aoff1);
            }
#pragma unroll
            for (int i = 0; i < 4; ++i)
#pragma unroll
                for (int ni = 0; ni < 4; ++ni) {
                    acc[h * 4 + i][ni] = __builtin_amdgcn_mfma_f32_16x16x32_f16(af[i][0], bf[ni][0], acc[h * 4 + i][ni], 0, 0, 0);
                    acc[h * 4 + i][ni] = __builtin_amdgcn_mfma_f32_16x16x32_f16(af[i][0], bf[ni][1], acc[h * 4 + i][ni], 0, 0, 0);
                    acc[h * 4 + i][ni] = __builtin_amdgcn_mfma_f32_16x16x32_f16(af[i][1], bf[ni][0], acc[h * 4 + i][ni], 0, 0, 0);
                }
        }
        __builtin_amdgcn_s_setprio(0);
        __builtin_amdgcn_sched_barrier(0);       // pin reads+MFMAs above barrier
        __builtin_amdgcn_s_barrier();            // all waves done reading cur buf
    }

    // epilogue: pre = acc*2^-12 + bias  (single scale: /(64*64))
    const float c12 = 1.0f / 4096.0f;
    float bv[4];
#pragma unroll
    for (int ni = 0; ni < 4; ++ni) bv[ni] = bias[n0 + wn * 64 + ni * 16 + rl];
#pragma unroll
    for (int mi = 0; mi < 8; ++mi)
#pragma unroll
        for (int ni = 0; ni < 4; ++ni)
#pragma unroll
            for (int r = 0; r < 4; ++r) {
                const int row = m0 + wm * 128 + mi * 16 + qw * 4 + r;
                const int col = n0 + wn * 64 + ni * 16 + rl;
                pre[(size_t)row * NSAE + col] = acc[mi][ni][r] * c12 + bv[ni];
            }
}

// ---------------- f32 fallback GEMM (R1, known-good) ----------------
__global__ __launch_bounds__(256) void gemm_pre_kernel(
    const float* __restrict__ A, const float* __restrict__ Bm,
    const float* __restrict__ bias, float* __restrict__ pre)
{
    __shared__ float As[16][128];
    __shared__ float Bs[16][128];
    const int bn = blockIdx.x * 128;
    const int bm = blockIdx.y * 128;
    const int tid = threadIdx.x;
    const int tx = tid & 15;
    const int ty = tid >> 4;

    float acc[8][8];
#pragma unroll
    for (int i = 0; i < 8; ++i)
#pragma unroll
        for (int j = 0; j < 8; ++j) acc[i][j] = 0.f;

    for (int k0 = 0; k0 < KDIM; k0 += 16) {
#pragma unroll
        for (int i = 0; i < 2; ++i) {
            const int idx = i * 256 + tid;
            const int r = idx >> 2;
            const int c = (idx & 3) << 2;
            const float4 v = *(const float4*)(A + (size_t)(bm + r) * KDIM + (k0 + c));
            As[c + 0][r] = v.x; As[c + 1][r] = v.y;
            As[c + 2][r] = v.z; As[c + 3][r] = v.w;
        }
#pragma unroll
        for (int i = 0; i < 2; ++i) {
            const int idx = i * 256 + tid;
            const int r = idx >> 5;
            const int c = (idx & 31) << 2;
            *(float4*)(&Bs[r][c]) = *(const float4*)(Bm + (size_t)(k0 + r) * NSAE + (bn + c));
        }
        __syncthreads();
#pragma unroll
        for (int kk = 0; kk < 16; ++kk) {
            const float4 a0 = *(const float4*)(&As[kk][ty * 8]);
            const float4 a1 = *(const float4*)(&As[kk][ty * 8 + 4]);
            const float4 b0 = *(const float4*)(&Bs[kk][tx * 8]);
            const float4 b1 = *(const float4*)(&Bs[kk][tx * 8 + 4]);
            const float av[8] = { a0.x, a0.y, a0.z, a0.w, a1.x, a1.y, a1.z, a1.w };
            const float bv[8] = { b0.x, b0.y, b0.z, b0.w, b1.x, b1.y, b1.z, b1.w };
#pragma unroll
            for (int i = 0; i < 8; ++i)
#pragma unroll
                for (int j = 0; j < 8; ++j)
                    acc[i][j] = fmaf(av[i], bv[j], acc[i][j]);
        }
        __syncthreads();
    }

    float bv8[8];
#pragma unroll
    for (int j = 0; j < 8; ++j) bv8[j] = bias[bn + tx * 8 + j];
#pragma unroll
    for (int i = 0; i < 8; ++i) {
        float4 o0, o1;
        o0.x = acc[i][0] + bv8[0]; o0.y = acc[i][1] + bv8[1];
        o0.z = acc[i][2] + bv8[2]; o0.w = acc[i][3] + bv8[3];
        o1.x = acc[i][4] + bv8[4]; o1.y = acc[i][5] + bv8[5];
        o1.z = acc[i][6] + bv8[6]; o1.w = acc[i][7] + bv8[7];
        const size_t off = (size_t)(bm + ty * 8 + i) * NSAE + bn + tx * 8;
        *(float4*)(pre + off) = o0;
        *(float4*)(pre + off + 4) = o1;
    }
}

// ---------------- per-row radix top-64, row held in registers ----------------
__global__ __launch_bounds__(256) void topk_kernel(
    const float* __restrict__ pre,
    int* __restrict__ tk_idx, float* __restrict__ tk_val,
    float* __restrict__ z)
{
    __shared__ unsigned hist[4][256];
    __shared__ int sel[NK];
    __shared__ float sval[NK];
    __shared__ int ties[256];
    __shared__ float tval[256];
    __shared__ unsigned sh_prefix, sh_want, sh_cnt, sh_tiecnt;

    const int b = blockIdx.x;
    const int tid = threadIdx.x;
    const int w = tid >> 6;
    const float* row = pre + (size_t)b * NSAE;
    float* zrow = z + (size_t)b * NSAE;

    if (tid == 0) { sh_prefix = 0u; sh_want = NK; sh_cnt = 0u; sh_tiecnt = 0u; }
    hist[0][tid] = 0u; hist[1][tid] = 0u; hist[2][tid] = 0u; hist[3][tid] = 0u;
    __syncthreads();

    // load row (registers) + zero z + MSB-8 histogram (pass 0)
    float4 rv[16];
#pragma unroll
    for (int j = 0; j < 16; ++j) {
        const int i = tid * 4 + j * 1024;
        rv[j] = *(const float4*)(row + i);
        *(float4*)(zrow + i) = make_float4(0.f, 0.f, 0.f, 0.f);
        atomicAdd(&hist[w][f2key(rv[j].x) >> 24], 1u);
        atomicAdd(&hist[w][f2key(rv[j].y) >> 24], 1u);
        atomicAdd(&hist[w][f2key(rv[j].z) >> 24], 1u);
        atomicAdd(&hist[w][f2key(rv[j].w) >> 24], 1u);
    }
    __syncthreads();
    hist[0][tid] += hist[1][tid] + hist[2][tid] + hist[3][tid];
    __syncthreads();
    if (tid == 0) {
        unsigned cum = 0u; int bsel = 0;
        for (int bin = 255; bin >= 0; --bin) {
            const unsigned c = hist[0][bin];
            if (cum + c >= NK) { bsel = bin; break; }
            cum += c;
        }
        sh_prefix = ((unsigned)bsel << 24);
        sh_want = NK - cum;
    }
    __syncthreads();

    for (int pass = 1; pass < 4; ++pass) {
        hist[0][tid] = 0u; hist[1][tid] = 0u; hist[2][tid] = 0u; hist[3][tid] = 0u;
        __syncthreads();
        const int shift = 24 - pass * 8;
        const unsigned mask = 0xFFFFFFFFu << (shift + 8);
        const unsigned pfx = sh_prefix;
#pragma unroll
        for (int j = 0; j < 16; ++j) {
            const float fv[4] = { rv[j].x, rv[j].y, rv[j].z, rv[j].w };
#pragma unroll
            for (int q = 0; q < 4; ++q) {
                const unsigned k = f2key(fv[q]);
                if ((k & mask) == pfx) atomicAdd(&hist[w][(k >> shift) & 0xFFu], 1u);
            }
        }
        __syncthreads();
        hist[0][tid] += hist[1][tid] + hist[2][tid] + hist[3][tid];
        __syncthreads();
        if (tid == 0) {
            const unsigned want = sh_want;
            unsigned cum = 0u; int bsel = 0;
            for (int bin = 255; bin >= 0; --bin) {
                const unsigned c = hist[0][bin];
                if (cum + c >= want) { bsel = bin; break; }
                cum += c;
            }
            sh_prefix |= ((unsigned)bsel << shift);
            sh_want = want - cum;
        }
        __syncthreads();
    }

    const unsigned T = sh_prefix;   // key of 64th-largest
#pragma unroll
    for (int j = 0; j < 16; ++j) {
        const float fv[4] = { rv[j].x, rv[j].y, rv[j].z, rv[j].w };
#pragma unroll
        for (int q = 0; q < 4; ++q) {
            const unsigned k = f2key(fv[q]);
            if (k > T) {
                const unsigned s = atomicAdd(&sh_cnt, 1u);
                sel[s] = tid * 4 + j * 1024 + q;
                sval[s] = fv[q];
            } else if (k == T) {
                const unsigned s = atomicAdd(&sh_tiecnt, 1u);
                if (s < 256u) { ties[s] = tid * 4 + j * 1024 + q; tval[s] = fv[q]; }
            }
        }
    }
    __syncthreads();
    if (tid == 0) {
        const unsigned tc = sh_tiecnt;
        const int n = (int)(tc < 256u ? tc : 256u);
        for (int a = 1; a < n; ++a) {           // sort ties by index (with value)
            const int v = ties[a]; const float fv = tval[a]; int c = a;
            while (c > 0 && ties[c - 1] > v) {
                ties[c] = ties[c - 1]; tval[c] = tval[c - 1]; --c;
            }
            ties[c] = v; tval[c] = fv;
        }
        const int base = (int)sh_cnt;
        const int want = (int)sh_want;
        for (int j = 0; j < want && j < n; ++j) {
            sel[base + j] = ties[j]; sval[base + j] = tval[j];
        }
    }
    __syncthreads();
    if (tid < NK) {
        const int myi = sel[tid];
        int rank = 0;                            // canonical (ascending-idx) order
#pragma unroll 1
        for (int j = 0; j < NK; ++j) rank += (sel[j] < myi) ? 1 : 0;
        const float v = fmaxf(sval[tid], 0.f);   // relu
        tk_idx[b * NK + rank] = myi;
        tk_val[b * NK + rank] = v;
        zrow[myi] = v;
    }
}

// ---------------- inverse permutation ----------------
__global__ __launch_bounds__(256) void invperm_kernel(
    const int* __restrict__ perm, int* __restrict__ ipos)
{
    const int i = blockIdx.x * 256 + threadIdx.x;
    if (i < NT * NSAE) {
        const int t = i >> 14;
        ipos[t * NSAE + perm[i]] = i & (NSAE - 1);
    }
}

// ---------------- sparse decode + SSE partials (t-major grid) ----------------
__global__ __launch_bounds__(256) void decode_kernel(
    const float* __restrict__ x,
    const int* __restrict__ tk_idx, const float* __restrict__ tk_val,
    const int* __restrict__ ipos,
    const float* __restrict__ Wd0, const float* __restrict__ bd0,
    const float* __restrict__ Wd1, const float* __restrict__ bd1,
    float* __restrict__ xhat, float* __restrict__ part0, float* __restrict__ part1)
{
    const int gbid = blockIdx.x;
    const int t = gbid >> 10;                   // t-major
    const int b = gbid & (NB - 1);
    const int bt = b * NT + t;
    const int tid = threadIdx.x;

    __shared__ int s_p[NK];
    __shared__ float s_v[NK];
    if (tid < NK) {
        const int s = tk_idx[b * NK + tid];
        s_v[tid] = tk_val[b * NK + tid];
        s_p[tid] = ipos[t * NSAE + s];
    }
    __syncthreads();

    float acc0[3], acc1[3];
#pragma unroll
    for (int r = 0; r < 3; ++r) {
        const int d = tid + 256 * r;
        acc0[r] = bd0[t * NDIN + d];
        acc1[r] = bd1[t * NDIN + d];
    }
    for (int j = 0; j < NK; ++j) {
        const int p = s_p[j];
        const float v = s_v[j];
        const float* w1 = Wd1 + ((size_t)p * NT + t) * NDIN;
#pragma unroll
        for (int r = 0; r < 3; ++r) acc1[r] = fmaf(v, w1[tid + 256 * r], acc1[r]);
        if (p < PFX0) {
            const float* w0 = Wd0 + ((size_t)p * NT + t) * NDIN;
#pragma unroll
            for (int r = 0; r < 3; ++r) acc0[r] = fmaf(v, w0[tid + 256 * r], acc0[r]);
        }
    }

    float e0 = 0.f, e1 = 0.f;
#pragma unroll
    for (int r = 0; r < 3; ++r) {
        const int d = tid + 256 * r;
        const float xv = x[(size_t)bt * NDIN + d];
        const float d0 = acc0[r] - xv;
        const float d1 = acc1[r] - xv;
        e0 = fmaf(d0, d0, e0);
        e1 = fmaf(d1, d1, e1);
        xhat[(size_t)bt * NDIN + d] = acc1[r];
    }

    __shared__ float r0[256];
    __shared__ float r1[256];
    r0[tid] = e0; r1[tid] = e1;
    __syncthreads();
    for (int w = 128; w > 0; w >>= 1) {
        if (tid < w) { r0[tid] += r0[tid + w]; r1[tid] += r1[tid + w]; }
        __syncthreads();
    }
    if (tid == 0) { part0[bt] = r0[0]; part1[bt] = r1[0]; }
}

// ---------------- final deterministic loss reduce ----------------
__global__ __launch_bounds__(256) void reduce_kernel(
    const float* __restrict__ part0, const float* __restrict__ part1,
    float* __restrict__ out_total)
{
    __shared__ double red[256];
    const int tid = threadIdx.x;
    double s = 0.0;
    for (int i = tid; i < NB * NT; i += 256)
        s += (double)part0[i] + (double)part1[i];
    red[tid] = s;
    __syncthreads();
    for (int w = 128; w > 0; w >>= 1) {
        if (tid < w) red[tid] += red[tid + w];
        __syncthreads();
    }
    if (tid == 0) out_total[0] = (float)(red[0] / ((double)NB * (double)(NT * 2)));
}

extern "C" void kernel_launch(void* const* d_in, const int* in_sizes, int n_in,
                              void* d_out, int out_size, void* d_ws, size_t ws_size,
                              hipStream_t stream)
{
    const float* x     = (const float*)d_in[0];
    const float* W_enc = (const float*)d_in[1];
    const float* b_enc = (const float*)d_in[2];
    const float* Wd0   = (const float*)d_in[3];
    const float* bd0   = (const float*)d_in[4];
    const float* Wd1   = (const float*)d_in[5];
    const float* bd1   = (const float*)d_in[6];
    const int*   perm  = (const int*)d_in[7];

    float* out       = (float*)d_out;
    float* out_total = out;
    float* out_xhat  = out + 1;
    float* out_z     = out + 1 + (size_t)NB * NT * NDIN;

    char* ws = (char*)d_ws;
    size_t off = 0;
    float* pre = (float*)(ws + off); off += (size_t)NB * NSAE * sizeof(float);

    const size_t szA2 = (size_t)NB * VKD * sizeof(_Float16);     // 12.6 MB
    const size_t szB2 = (size_t)NSAE * VKD * sizeof(_Float16);   // 201.3 MB
    _Float16* A2 = (_Float16*)(ws + off);
    _Float16* B2 = (_Float16*)(ws + off + szA2);
    const size_t off_splits_end = off + szA2 + szB2;

    const bool fast = (ws_size >= off_splits_end +
        ((size_t)NB * NK * 8 + (size_t)NT * NSAE * 4 + (size_t)NB * NT * 8));
    size_t tail = fast ? off_splits_end : off;
    int*   tk_idx = (int*)(ws + tail);   tail += (size_t)NB * NK * sizeof(int);
    float* tk_val = (float*)(ws + tail); tail += (size_t)NB * NK * sizeof(float);
    int*   ipos   = (int*)(ws + tail);   tail += (size_t)NT * NSAE * sizeof(int);
    float* part0  = (float*)(ws + tail); tail += (size_t)NB * NT * sizeof(float);
    float* part1  = (float*)(ws + tail);

    if (fast) {
        conv_a_kernel<<<(NB * KDIM) / (256 * 4), 256, 0, stream>>>(x, A2);
        conv_bt_kernel<<<dim3(NSAE / 64, KDIM / 64), 256, 0, stream>>>(W_enc, B2);
        gemm_f16split_kernel<<<256, 512, 0, stream>>>(A2, B2, b_enc, pre);
    } else {
        gemm_pre_kernel<<<dim3(NSAE / 128, NB / 128), 256, 0, stream>>>(x, W_enc, b_enc, pre);
    }
    invperm_kernel<<<(NT * NSAE) / 256, 256, 0, stream>>>(perm, ipos);
    topk_kernel<<<NB, 256, 0, stream>>>(pre, tk_idx, tk_val, out_z);
    decode_kernel<<<NB * NT, 256, 0, stream>>>(x, tk_idx, tk_val, ipos,
                                               Wd0, bd0, Wd1, bd1,
                                               out_xhat, part0, part1);
    reduce_kernel<<<1, 256, 0, stream>>>(part0, part1, out_total);
}